// Round 16
// baseline (392.166 us; speedup 1.0000x reference)
//
#include <hip/hip_runtime.h>

#define HDIM 224
#define WDIM 224
#define PPIX 50176      // 224*224
#define BATCH 8
#define NPIX 401408     // 8*50176
#define KTOP 15052      // max(int(0.3*224*224), 64)
#define NELEM 25690112  // 8*64*50176
#define NBLK 6272       // 8*784 strip grid
#define NBAND 14        // 224/16
#define NDWBLK 7168     // 8*64*14
#define NCHUNK 49       // PPIX / 1024

typedef __attribute__((ext_vector_type(8))) short bf8_t;
typedef __attribute__((ext_vector_type(4))) float f4_t;
typedef __attribute__((ext_vector_type(8))) unsigned short us8_t;
typedef __attribute__((ext_vector_type(4))) unsigned short us4_t;
#define MFMA_BF16 __builtin_amdgcn_mfma_f32_16x16x32_bf16

// round-to-nearest-even f32 -> bf16
__device__ inline unsigned short f2bf(float f) {
    unsigned int u = __float_as_uint(f);
    return (unsigned short)((u + 0x7FFFu + ((u >> 16) & 1u)) >> 16);
}
__device__ inline float bf2f(unsigned short u) {
    return __uint_as_float(((unsigned int)u) << 16);
}

// LDS 64x64 bf16 matrix: 128B rows = 8 chunks(16B); physical chunk = k ^ g(r),
// g(r) = (r ^ (r>>3)) & 7. All fragment reads / staged writes are bank-uniform.
__device__ inline int ldsg(int r) { return ((r >> 3) ^ r) & 7; }

// stage a 64x64 fp32 matrix into swizzled bf16 LDS. 256 threads.
__device__ inline void stage_w64(const float* __restrict__ W, char* sWc, int t) {
    int o = t >> 2, cq = t & 3, c0 = cq * 16;
    const float4* src = (const float4*)(W + o * 64 + c0);
    float4 v0 = src[0], v1 = src[1], v2 = src[2], v3 = src[3];
    bf8_t p0, p1;
    p0[0] = (short)f2bf(v0.x); p0[1] = (short)f2bf(v0.y);
    p0[2] = (short)f2bf(v0.z); p0[3] = (short)f2bf(v0.w);
    p0[4] = (short)f2bf(v1.x); p0[5] = (short)f2bf(v1.y);
    p0[6] = (short)f2bf(v1.z); p0[7] = (short)f2bf(v1.w);
    p1[0] = (short)f2bf(v2.x); p1[1] = (short)f2bf(v2.y);
    p1[2] = (short)f2bf(v2.z); p1[3] = (short)f2bf(v2.w);
    p1[4] = (short)f2bf(v3.x); p1[5] = (short)f2bf(v3.y);
    p1[6] = (short)f2bf(v3.z); p1[7] = (short)f2bf(v3.w);
    int g = ldsg(o);
    *(bf8_t*)(sWc + o * 128 + (((2 * cq) ^ g) << 4)) = p0;
    *(bf8_t*)(sWc + o * 128 + (((2 * cq + 1) ^ g) << 4)) = p1;
}

// C[64o x 64p] = W(64x64, sWc) @ P([p][c], sPc); wave owns rows m0..m0+15.
__device__ inline void mfma64(const char* sWc, const char* sPc, int l, int m0, f4_t acc[4]) {
    int lr = l & 15, lg = l >> 4;
    int ra = m0 + lr, ga = ldsg(ra);
    const char* abase = sWc + ra * 128;
    bf8_t a0 = *(const bf8_t*)(abase + ((lg ^ ga) << 4));
    bf8_t a1 = *(const bf8_t*)(abase + (((lg + 4) ^ ga) << 4));
    #pragma unroll
    for (int nt = 0; nt < 4; nt++) {
        int rb = nt * 16 + lr, gb = ldsg(rb);
        const char* bbase = sPc + rb * 128;
        bf8_t b0 = *(const bf8_t*)(bbase + ((lg ^ gb) << 4));
        bf8_t b1 = *(const bf8_t*)(bbase + (((lg + 4) ^ gb) << 4));
        f4_t c = {0.f, 0.f, 0.f, 0.f};
        c = MFMA_BF16(a0, b0, c, 0, 0, 0);
        c = MFMA_BF16(a1, b1, c, 0, 0, 0);
        acc[nt] = c;
    }
}

// ---------------- prep: tiny derived coefficients + topk state init ----------
__global__ __launch_bounds__(256) void prep_kernel(
    const float* __restrict__ w_in, const float* __restrict__ b_in,
    const float* __restrict__ imp_w1, const float* __restrict__ imp_b1,
    const float* __restrict__ fin_w, const float* __restrict__ fin_b,
    float* __restrict__ coeffs, unsigned int* __restrict__ ghist,
    unsigned int* __restrict__ pfx, int* __restrict__ rem)
{
    int t = threadIdx.x;
    if (t < 16) {
        float a = 0.f, d = 0.f;
        for (int c = 0; c < 64; c++) {
            a += imp_w1[t * 64 + c] * w_in[64 + c];
            d += imp_w1[t * 64 + c] * b_in[64 + c];
        }
        coeffs[t] = a;
        coeffs[16 + t] = d + imp_b1[t];
    }
    if (t < 64) {
        float a = 0.f, d = 0.f;
        for (int c = 0; c < 64; c++) {
            a += fin_w[t * 64 + c] * w_in[c];
            d += fin_w[t * 64 + c] * b_in[c];
        }
        coeffs[32 + t] = a;
        coeffs[96 + t] = d + fin_b[t];
    }
    for (int i = t; i < 2048; i += 256) ghist[i] = 0u;
    if (t < BATCH) { pfx[t] = 0u; rem[t] = KTOP; }
}

// ---------------- importance map: sigmoid(conv3x3(relu(x*a+d), w2)+b2) --------
__global__ __launch_bounds__(256) void imp_kernel(
    const float* __restrict__ x, const float* __restrict__ coeffs,
    const float* __restrict__ imp_w2, const float* __restrict__ imp_b2,
    float* __restrict__ imp)
{
    int idx = blockIdx.x * 256 + threadIdx.x;
    int b = idx / PPIX, p = idx % PPIX;
    int h = p / WDIM, w = p % WDIM;
    float acc = imp_b2[0];
    #pragma unroll
    for (int ky = 0; ky < 3; ky++) {
        int hh = h + ky - 1;
        float okh = (hh >= 0 && hh < HDIM) ? 1.f : 0.f;
        int hc = min(max(hh, 0), HDIM - 1);
        #pragma unroll
        for (int kx = 0; kx < 3; kx++) {
            int ww = w + kx - 1;
            float ok = okh * ((ww >= 0 && ww < WDIM) ? 1.f : 0.f);
            int wc = min(max(ww, 0), WDIM - 1);
            float xv = x[b * PPIX + hc * WDIM + wc] * ok;
            #pragma unroll
            for (int c = 0; c < 16; c++) {
                float r = fmaxf(xv * coeffs[c] + coeffs[16 + c] * ok, 0.f);
                acc += r * imp_w2[c * 9 + ky * 3 + kx];
            }
        }
    }
    imp[idx] = 1.f / (1.f + expf(-acc));
}

// ---------------- parallel exact top-k: radix histogram pass ------------------
__global__ __launch_bounds__(256) void topk_hist(
    const float* __restrict__ imp, const unsigned int* __restrict__ pfx,
    unsigned int* __restrict__ ghist, int shift)
{
    int b = blockIdx.x / NCHUNK, ch = blockIdx.x % NCHUNK;
    int t = threadIdx.x;
    __shared__ unsigned int hist[256];
    hist[t] = 0u;
    __syncthreads();
    unsigned int prefix = pfx[b];
    unsigned int himask = (shift == 24) ? 0u : (0xFFFFFFFFu << (shift + 8));
    float4 v = ((const float4*)(imp + b * PPIX + ch * 1024))[t];
    unsigned int bb[4] = {__float_as_uint(v.x), __float_as_uint(v.y),
                          __float_as_uint(v.z), __float_as_uint(v.w)};
    #pragma unroll
    for (int k = 0; k < 4; k++)
        if ((bb[k] & himask) == prefix)
            atomicAdd(&hist[(bb[k] >> shift) & 255u], 1u);
    __syncthreads();
    unsigned int c = hist[t];
    if (c) atomicAdd(&ghist[b * 256 + t], c);
}

// ---------------- top-k: select bin, update prefix/remaining, zero hist -------
__global__ __launch_bounds__(256) void topk_select(
    unsigned int* __restrict__ ghist, unsigned int* __restrict__ pfx,
    int* __restrict__ rem, int shift)
{
    int b = blockIdx.x;
    int t = threadIdx.x;
    __shared__ unsigned int h[256];
    h[t] = ghist[b * 256 + t];
    ghist[b * 256 + t] = 0u;
    __syncthreads();
    if (t == 0) {
        int r = rem[b];
        unsigned int bsel = 0u;
        for (int bin = 255; bin >= 0; bin--) {
            int c = (int)h[bin];
            if (c >= r) { bsel = (unsigned int)bin; break; }
            r -= c;
        }
        rem[b] = r;
        pfx[b] |= bsel << shift;
    }
}

// ---------------- top-k: write mask for >T, count ties per chunk --------------
__global__ __launch_bounds__(256) void topk_mask1(
    const float* __restrict__ imp, const unsigned int* __restrict__ pfx,
    float* __restrict__ mask, int* __restrict__ blocktie)
{
    int b = blockIdx.x / NCHUNK, ch = blockIdx.x % NCHUNK;
    int t = threadIdx.x;
    unsigned int T = pfx[b];
    float4 v = ((const float4*)(imp + b * PPIX + ch * 1024))[t];
    unsigned int bb[4] = {__float_as_uint(v.x), __float_as_uint(v.y),
                          __float_as_uint(v.z), __float_as_uint(v.w)};
    float4 mo;
    float* mp = &mo.x;
    int cnt = 0;
    #pragma unroll
    for (int k = 0; k < 4; k++) {
        mp[k] = (bb[k] > T) ? 1.f : 0.f;
        cnt += (bb[k] == T) ? 1 : 0;
    }
    ((float4*)(mask + b * PPIX + ch * 1024))[t] = mo;
    #pragma unroll
    for (int off = 32; off > 0; off >>= 1) cnt += __shfl_down(cnt, off);
    __shared__ int ws4[4];
    int lane = t & 63, wv = t >> 6;
    if (lane == 0) ws4[wv] = cnt;
    __syncthreads();
    if (t == 0) blocktie[b * NCHUNK + ch] = ws4[0] + ws4[1] + ws4[2] + ws4[3];
}

// ---------------- top-k: set first `rem` ties in index order ------------------
__global__ __launch_bounds__(256) void topk_mask2(
    const float* __restrict__ imp, const unsigned int* __restrict__ pfx,
    const int* __restrict__ rem_, const int* __restrict__ blocktie,
    float* __restrict__ mask)
{
    int b = blockIdx.x;
    int t = threadIdx.x, lane = t & 63, wv = t >> 6;
    unsigned int T = pfx[b];
    int rem = rem_[b];
    __shared__ int sbase[NCHUNK], scnt[NCHUNK];
    if (t == 0) {
        int s = 0;
        for (int i = 0; i < NCHUNK; i++) {
            sbase[i] = s;
            int c = blocktie[b * NCHUNK + i];
            scnt[i] = c;
            s += c;
        }
    }
    __syncthreads();
    __shared__ int wtot[4];
    for (int ch = 0; ch < NCHUNK; ch++) {
        if (scnt[ch] == 0) continue;
        int base = sbase[ch];
        if (base >= rem) break;
        for (int g = 0; g < 4; g++) {
            int i = b * PPIX + ch * 1024 + g * 256 + t;
            int flag = (__float_as_uint(imp[i]) == T) ? 1 : 0;
            unsigned long long bal = __ballot(flag);
            if (lane == 0) wtot[wv] = __popcll(bal);
            __syncthreads();
            int wbase = 0, tot = 0;
            for (int q = 0; q < 4; q++) { int c = wtot[q]; if (q < wv) wbase += c; tot += c; }
            if (flag && base + wbase + __popcll(bal & ((1ull << lane) - 1ull)) < rem)
                mask[i] = 1.f;
            base += tot;
            __syncthreads();
        }
    }
}

// ---------------- level 0: masked dwconv3x3 -> MFMA 1x1, y0(bf16) + partials --
__global__ __launch_bounds__(256, 4) void level0_kernel(
    const float* __restrict__ x, const float* __restrict__ mask,
    const float* __restrict__ w_in, const float* __restrict__ b_in,
    const float* __restrict__ dw_w, const float* __restrict__ pw_w,
    const float* __restrict__ pw_b,
    unsigned short* __restrict__ y_out, float* __restrict__ partials)
{
    __shared__ __align__(16) short sW[4096];
    __shared__ __align__(16) short sP[4096];
    __shared__ float sred[128];
    __shared__ float sBias[64];
    char* sWc = (char*)sW; char* sPc = (char*)sP;
    int t = threadIdx.x;
    int swz = (blockIdx.x & 7) * 784 + (blockIdx.x >> 3);
    int b = swz / 784;
    int l = t & 63, og = t >> 6;
    int p0 = (swz % 784) * 64;
    int p = p0 + l;
    int h = p / WDIM, w = p % WDIM;
    stage_w64(pw_w, sWc, t);
    if (t < 64) sBias[t] = pw_b[t];

    int rowoff[3]; float okhf[3];
    int wcs[3]; float okwf[3];
    #pragma unroll
    for (int k = 0; k < 3; k++) {
        int hh = h + k - 1;
        okhf[k] = (hh >= 0 && hh < HDIM) ? 1.f : 0.f;
        rowoff[k] = min(max(hh, 0), HDIM - 1) * WDIM;
        int ww = w + k - 1;
        okwf[k] = (ww >= 0 && ww < WDIM) ? 1.f : 0.f;
        wcs[k] = min(max(ww, 0), WDIM - 1);
    }
    float mv[9], mxv[9];
    const float* mb = mask + b * PPIX;
    const float* xb = x + b * PPIX;
    #pragma unroll
    for (int ky = 0; ky < 3; ky++) {
        #pragma unroll
        for (int kx = 0; kx < 3; kx++) {
            int a = rowoff[ky] + wcs[kx];
            float mm = mb[a] * (okhf[ky] * okwf[kx]);
            mv[ky * 3 + kx] = mm;
            mxv[ky * 3 + kx] = mm * xb[a];
        }
    }
    bf8_t pk0, pk1;
    #pragma unroll
    for (int j = 0; j < 16; j++) {
        int c = og * 16 + j;
        float wk = w_in[64 + c], bk = b_in[64 + c];
        const float* dwr = dw_w + c * 9;
        float a0 = 0.f, a1 = 0.f;
        #pragma unroll
        for (int tp = 0; tp < 9; tp++) {
            float dv = dwr[tp];
            a0 += dv * mxv[tp];
            a1 += dv * mv[tp];
        }
        unsigned short bv = f2bf(wk * a0 + bk * a1);
        if (j < 8) pk0[j] = (short)bv; else pk1[j - 8] = (short)bv;
    }
    int gl = ldsg(l);
    *(bf8_t*)(sPc + l * 128 + (((2 * og) ^ gl) << 4)) = pk0;
    *(bf8_t*)(sPc + l * 128 + (((2 * og + 1) ^ gl) << 4)) = pk1;
    __syncthreads();

    int m0 = og * 16, lr = l & 15, lg = l >> 4;
    f4_t acc[4];
    mfma64(sWc, sPc, l, m0, acc);
    unsigned short* ybase = y_out + (size_t)b * 64 * PPIX + p0;
    #pragma unroll
    for (int r = 0; r < 4; r++) {
        int o = m0 + 4 * lg + r;
        float bias = sBias[o];
        float s = 0.f, s2 = 0.f;
        #pragma unroll
        for (int nt = 0; nt < 4; nt++) {
            float yv = acc[nt][r] + bias;
            ybase[(size_t)o * PPIX + nt * 16 + lr] = f2bf(yv);
            s += yv; s2 += yv * yv;
        }
        #pragma unroll
        for (int m = 1; m < 16; m <<= 1) {
            s += __shfl_xor(s, m);
            s2 += __shfl_xor(s2, m);
        }
        if (lr == 0) { sred[2 * o] = s; sred[2 * o + 1] = s2; }
    }
    __syncthreads();
    if (t < 128) partials[(size_t)blockIdx.x * 128 + t] = sred[t];
}

// ---------------- dilated dwconv: bf16 in/out, register-sliding ---------------
// compute: row-fastest (row=t&15, xs=t>>4) -> b128 reads spread over all 8
// bank quads. staging: ONE float4 store per item over LR*56 float4-columns,
// qq-fastest -> store quad stride 1 -> conflict-free; matching us4 global
// loads stay fully coalesced (consecutive lanes, consecutive 8B).
template<int KSZ, int DIL>
__global__ __launch_bounds__(256, 4) void dw_kernel(
    const unsigned short* __restrict__ in, const float* __restrict__ bnp,
    const float* __restrict__ dw_w, unsigned short* __restrict__ out)
{
    constexpr int PAD = (KSZ / 2) * DIL;
    constexpr int BH = 16;
    constexpr int LR = BH + 2 * PAD;
    constexpr int SW = WDIM + 2 * PAD + 4;    // %4==0; %32 = 28 (7,4) / 12 (5,2)
    constexpr int SEG = 16 + 2 * PAD;
    __shared__ float sIn[LR * SW];

    int t = threadIdx.x;
    int swz = (blockIdx.x & 7) * (NDWBLK / 8) + (blockIdx.x >> 3);
    int bc = swz / NBAND, band = swz % NBAND;
    int c = bc & 63;
    int r0 = band * BH;
    float sc = bnp[c], sh = bnp[64 + c];
    const unsigned short* plane = in + (size_t)bc * PPIX;

    constexpr int PADC = SW - WDIM;
    for (int i = t; i < LR * PADC; i += 256) {
        int r = i / PADC, cc = i % PADC;
        int col = (cc < PAD) ? cc : (cc + WDIM);
        sIn[r * SW + col] = 0.f;
    }
    for (int i = t; i < LR * 56; i += 256) {
        int sr = i / 56, qq = i % 56;
        int gr = r0 - PAD + sr;
        float4 a = {0.f, 0.f, 0.f, 0.f};
        if (gr >= 0 && gr < HDIM) {
            us4_t v = *(const us4_t*)(plane + gr * WDIM + 4 * qq);
            a.x = fmaxf(sc * bf2f(v[0]) + sh, 0.f);
            a.y = fmaxf(sc * bf2f(v[1]) + sh, 0.f);
            a.z = fmaxf(sc * bf2f(v[2]) + sh, 0.f);
            a.w = fmaxf(sc * bf2f(v[3]) + sh, 0.f);
        }
        *(float4*)(sIn + sr * SW + PAD + 4 * qq) = a;
    }
    __syncthreads();

    if (t < 224) {   // no barriers below; idle tail predicated
        const float* dwr = dw_w + c * KSZ * KSZ;
        float wk[KSZ * KSZ];
        #pragma unroll
        for (int i = 0; i < KSZ * KSZ; i++) wk[i] = dwr[i];

        int row = t & 15, xs = t >> 4;     // row-fastest: 16 rows x 14 strips
        int x0 = xs * 16;
        float acc[16];
        #pragma unroll
        for (int j = 0; j < 16; j++) acc[j] = 0.f;
        #pragma unroll
        for (int ky = 0; ky < KSZ; ky++) {
            const float4* srow = (const float4*)(sIn + (row + ky * DIL) * SW + x0);
            float s[SEG];
            #pragma unroll
            for (int i = 0; i < SEG / 4; i++) ((float4*)s)[i] = srow[i];
            #pragma unroll
            for (int kx = 0; kx < KSZ; kx++) {
                float wv = wk[ky * KSZ + kx];
                #pragma unroll
                for (int j = 0; j < 16; j++)
                    acc[j] += s[j + DIL * kx] * wv;
            }
        }
        us8_t o0, o1;
        #pragma unroll
        for (int j = 0; j < 8; j++) { o0[j] = f2bf(acc[j]); o1[j] = f2bf(acc[8 + j]); }
        unsigned short* orow = out + (size_t)bc * PPIX + (r0 + row) * WDIM + x0;
        *(us8_t*)orow = o0;
        *(us8_t*)(orow + 8) = o1;
    }
}

// ---------------- pointwise 64x64 MFMA matvec, OUT-OF-PLACE, + bn partials ----
__global__ __launch_bounds__(256, 4) void pw_kernel(
    const float* __restrict__ pw_w, const float* __restrict__ pw_b,
    const unsigned short* __restrict__ src_y, unsigned short* __restrict__ dst_y,
    float* __restrict__ partials)
{
    __shared__ __align__(16) short sW[4096];
    __shared__ __align__(16) short sP[4096];
    __shared__ float sred[128];
    __shared__ float sBias[64];
    char* sWc = (char*)sW; char* sPc = (char*)sP;
    int t = threadIdx.x;
    int swz = (blockIdx.x & 7) * 784 + (blockIdx.x >> 3);
    int b = swz / 784;
    int p0 = (swz % 784) * 64;
    stage_w64(pw_w, sWc, t);
    if (t < 64) sBias[t] = pw_b[t];

    const unsigned short* sbase_g = src_y + (size_t)b * 64 * PPIX + p0;
    unsigned short* dbase_g = dst_y + (size_t)b * 64 * PPIX + p0;
    {
        int c = t >> 2, pg = t & 3;
        const unsigned short* src = sbase_g + (size_t)c * PPIX + 16 * pg;
        us8_t v0 = *(const us8_t*)src;
        us8_t v1 = *(const us8_t*)(src + 8);
        int kc = c >> 3, cb = 2 * (c & 7);
        #pragma unroll
        for (int e = 0; e < 16; e++) {
            int r = 16 * pg + e;
            int gr = ldsg(r);
            unsigned short val = (e < 8) ? (unsigned short)v0[e] : (unsigned short)v1[e - 8];
            *(unsigned short*)(sPc + r * 128 + ((kc ^ gr) << 4) + cb) = val;
        }
    }
    __syncthreads();

    int l = t & 63, wv = t >> 6, m0 = wv * 16;
    int lr = l & 15, lg = l >> 4;
    f4_t acc[4];
    mfma64(sWc, sPc, l, m0, acc);
    #pragma unroll
    for (int r = 0; r < 4; r++) {
        int o = m0 + 4 * lg + r;
        float bias = sBias[o];
        float s = 0.f, s2 = 0.f;
        #pragma unroll
        for (int nt = 0; nt < 4; nt++) {
            float yv = acc[nt][r] + bias;
            dbase_g[(size_t)o * PPIX + nt * 16 + lr] = f2bf(yv);
            s += yv; s2 += yv * yv;
        }
        #pragma unroll
        for (int m = 1; m < 16; m <<= 1) {
            s += __shfl_xor(s, m);
            s2 += __shfl_xor(s2, m);
        }
        if (lr == 0) { sred[2 * o] = s; sred[2 * o + 1] = s2; }
    }
    __syncthreads();
    if (t < 128) partials[(size_t)blockIdx.x * 128 + t] = sred[t];
}

// ---------------- bn finalize: tree-reduce partials, one block per channel ----
__global__ __launch_bounds__(256) void bnfin_kernel(
    const float* __restrict__ partials,
    const float* __restrict__ g, const float* __restrict__ be,
    float* __restrict__ bnp)
{
    int c = blockIdx.x;
    int t = threadIdx.x;
    float s = 0.f, s2 = 0.f;
    for (int blk = t; blk < NBLK; blk += 256) {
        s  += partials[(size_t)blk * 128 + 2 * c];
        s2 += partials[(size_t)blk * 128 + 2 * c + 1];
    }
    #pragma unroll
    for (int off = 32; off > 0; off >>= 1) {
        s += __shfl_down(s, off);
        s2 += __shfl_down(s2, off);
    }
    __shared__ float wsm[8];
    int lane = t & 63, wv = t >> 6;
    if (lane == 0) { wsm[wv] = s; wsm[4 + wv] = s2; }
    __syncthreads();
    if (t == 0) {
        s = wsm[0] + wsm[1] + wsm[2] + wsm[3];
        s2 = wsm[4] + wsm[5] + wsm[6] + wsm[7];
        const float inv_n = 1.f / (float)NPIX;
        float mu = s * inv_n;
        float var = s2 * inv_n - mu * mu;
        float sc = g[c] * rsqrtf(var + 1e-5f);
        bnp[c] = sc;
        bnp[64 + c] = be[c] - mu * sc;
    }
}

// ---------------- K_global: per (b,c) spatial mean of relu(bn(y2)) ------------
__global__ __launch_bounds__(1024) void kglobal_kernel(
    const unsigned short* __restrict__ y2, const float* __restrict__ bnp2,
    float* __restrict__ kg)
{
    int bc = blockIdx.x;
    int c = bc & 63;
    int t = threadIdx.x;
    const unsigned short* row = y2 + (size_t)bc * PPIX;
    float sc = bnp2[c], sh = bnp2[64 + c];
    float s = 0.f;
    for (int ii = t; ii < PPIX / 8; ii += 1024) {
        us8_t v = *(const us8_t*)(row + 8 * ii);
        #pragma unroll
        for (int k = 0; k < 8; k++) s += fmaxf(sc * bf2f(v[k]) + sh, 0.f);
    }
    #pragma unroll
    for (int off = 32; off > 0; off >>= 1) s += __shfl_down(s, off);
    __shared__ float wsum[16];
    int lane = t & 63, wv = t >> 6;
    if (lane == 0) wsum[wv] = s;
    __syncthreads();
    if (t == 0) {
        float tot = 0.f;
        #pragma unroll
        for (int q = 0; q < 16; q++) tot += wsum[q];
        kg[bc] = tot * (1.f / (float)PPIX);
    }
}

// ---------------- final: aggregate + MFMA V + QV + MFMA O + x_proj ------------
__global__ __launch_bounds__(256, 4) void final_kernel(
    const float* __restrict__ x, const float* __restrict__ w_in,
    const float* __restrict__ b_in,
    const unsigned short* __restrict__ y0, const unsigned short* __restrict__ y1,
    const unsigned short* __restrict__ y2,
    const float* __restrict__ bnp, const float* __restrict__ kg,
    const float* __restrict__ val_w, const float* __restrict__ val_b,
    const float* __restrict__ out_w, const float* __restrict__ out_b,
    const float* __restrict__ coeffs, float* __restrict__ out)
{
    __shared__ __align__(16) short sVW[4096];
    __shared__ __align__(16) short sOW[4096];
    __shared__ __align__(16) short sP[4096];
    __shared__ float sxv[64], sG[320];   // sG stride-5: 2-way max bank alias
    __shared__ float sQW[64], sQB[64], sVB[64], sOB[64], sC1[64], sC2[64];
    char* sVWc = (char*)sVW; char* sOWc = (char*)sOW; char* sPc = (char*)sP;
    int t = threadIdx.x;
    int blk = blockIdx.x;
    int b = blk / 784;
    int l = t & 63, wv = t >> 6;
    int p0 = (blk % 784) * 64;
    stage_w64(val_w, sVWc, t);
    stage_w64(out_w, sOWc, t);
    if (t < 64) {
        sQW[t] = w_in[t]; sQB[t] = b_in[t];
        sVB[t] = val_b[t]; sOB[t] = out_b[t];
        sC1[t] = coeffs[32 + t]; sC2[t] = coeffs[96 + t];
        float xv = x[b * PPIX + p0 + t];
        sxv[t] = xv;
        float g0 = xv * w_in[128] + b_in[128];
        float g1 = xv * w_in[129] + b_in[129];
        float g2 = xv * w_in[130] + b_in[130];
        float g3 = xv * w_in[131] + b_in[131];
        float mx = fmaxf(fmaxf(g0, g1), fmaxf(g2, g3));
        float e0 = expf(g0 - mx), e1 = expf(g1 - mx);
        float e2 = expf(g2 - mx), e3 = expf(g3 - mx);
        float inv = 1.f / (e0 + e1 + e2 + e3);
        sG[5 * t + 0] = e0 * inv;
        sG[5 * t + 1] = e1 * inv;
        sG[5 * t + 2] = e2 * inv;
        sG[5 * t + 3] = e3 * inv;
    }
    __syncthreads();

    // P staging: thread = (channel c, 16-pixel group pg), us8 vector loads
    {
        int c = t >> 2, pg = t & 3;
        size_t base = (size_t)(b * 64 + c) * PPIX + p0 + 16 * pg;
        us8_t a0 = *(const us8_t*)(y0 + base);
        us8_t a1 = *(const us8_t*)(y0 + base + 8);
        us8_t q0 = *(const us8_t*)(y1 + base);
        us8_t q1 = *(const us8_t*)(y1 + base + 8);
        us8_t r0 = *(const us8_t*)(y2 + base);
        us8_t r1 = *(const us8_t*)(y2 + base + 8);
        float s0 = bnp[c],       h0 = bnp[64 + c];
        float s1 = bnp[128 + c], h1 = bnp[192 + c];
        float s2 = bnp[256 + c], h2 = bnp[320 + c];
        float kgc = kg[b * 64 + c];
        int kc = c >> 3, cb = 2 * (c & 7);
        #pragma unroll
        for (int e = 0; e < 16; e++) {
            unsigned short u0 = (e < 8) ? (unsigned short)a0[e] : (unsigned short)a1[e - 8];
            unsigned short u1 = (e < 8) ? (unsigned short)q0[e] : (unsigned short)q1[e - 8];
            unsigned short u2 = (e < 8) ? (unsigned short)r0[e] : (unsigned short)r1[e - 8];
            float f0 = fmaxf(s0 * bf2f(u0) + h0, 0.f);
            float f1 = fmaxf(s1 * bf2f(u1) + h1, 0.f);
            float f2 = fmaxf(s2 * bf2f(u2) + h2, 0.f);
            int r = 16 * pg + e;
            float kf = sG[5 * r] * f0 + sG[5 * r + 1] * f1
                     + sG[5 * r + 2] * f2 + sG[5 * r + 3] * kgc;
            int gr = ldsg(r);
            *(unsigned short*)(sPc + r * 128 + ((kc ^ gr) << 4) + cb) = f2bf(kf);
        }
    }
    __syncthreads();

    int m0 = wv * 16, lr = l & 15, lg = l >> 4;
    f4_t accV[4];
    mfma64(sVWc, sPc, l, m0, accV);
    __syncthreads();   // all P reads done before QV overwrite

    #pragma unroll
    for (int nt = 0; nt < 4; nt++) {
        float xvp = sxv[nt * 16 + lr];
        us4_t q4;
        #pragma unroll
        for (int r = 0; r < 4; r++) {
            int o = m0 + 4 * lg + r;
            float V = accV[nt][r] + sVB[o];
            float q = xvp * sQW[o] + sQB[o];
            q4[r] = f2bf(q * V);
        }
        int rb = nt * 16 + lr, gb = ldsg(rb);
        int kc = 2 * wv + (lg >> 1);
        *(us4_t*)(sPc + rb * 128 + ((kc ^ gb) << 4) + 8 * (lg & 1)) = q4;
    }
    __syncthreads();

    f4_t accO[4];
    mfma64(sOWc, sPc, l, m0, accO);
    #pragma unroll
    for (int nt = 0; nt < 4; nt++) {
        float xvp = sxv[nt * 16 + lr];
        #pragma unroll
        for (int r = 0; r < 4; r++) {
            int o = m0 + 4 * lg + r;
            out[(size_t)(b * 64 + o) * PPIX + p0 + nt * 16 + lr] =
                accO[nt][r] + sOB[o] + xvp * sC1[o] + sC2[o];
        }
    }
}

extern "C" void kernel_launch(void* const* d_in, const int* in_sizes, int n_in,
                              void* d_out, int out_size, void* d_ws, size_t ws_size,
                              hipStream_t stream)
{
    (void)in_sizes; (void)n_in; (void)out_size; (void)ws_size;
    const float* x      = (const float*)d_in[0];
    const float* w_in   = (const float*)d_in[1];
    const float* b_in   = (const float*)d_in[2];
    const float* dw0    = (const float*)d_in[3];
    const float* pw0_w  = (const float*)d_in[4];
    const float* pw0_b  = (const float*)d_in[5];
    const float* bn0_g  = (const float*)d_in[6];
    const float* bn0_b  = (const float*)d_in[7];
    const float* dw1    = (const float*)d_in[8];
    const float* pw1_w  = (const float*)d_in[9];
    const float* pw1_b  = (const float*)d_in[10];
    const float* bn1_g  = (const float*)d_in[11];
    const float* bn1_b  = (const float*)d_in[12];
    const float* dw2    = (const float*)d_in[13];
    const float* pw2_w  = (const float*)d_in[14];
    const float* pw2_b  = (const float*)d_in[15];
    const float* bn2_g  = (const float*)d_in[16];
    const float* bn2_b  = (const float*)d_in[17];
    const float* imp_w1 = (const float*)d_in[18];
    const float* imp_b1 = (const float*)d_in[19];
    const float* imp_w2 = (const float*)d_in[20];
    const float* imp_b2 = (const float*)d_in[21];
    const float* val_w  = (const float*)d_in[22];
    const float* val_b  = (const float*)d_in[23];
    const float* out_w  = (const float*)d_in[24];
    const float* out_b  = (const float*)d_in[25];
    const float* fin_w  = (const float*)d_in[26];
    const float* fin_b  = (const float*)d_in[27];

    unsigned short* y0 = (unsigned short*)d_ws;
    unsigned short* y1 = y0 + (size_t)NELEM;
    unsigned short* y2 = y1 + (size_t)NELEM;
    unsigned short* yt = y2 + (size_t)NELEM;           // dwconv temp
    float* imp  = (float*)(yt + (size_t)NELEM);
    float* mask = imp + NPIX;
    float* partials = mask + NPIX;                // 6272*128
    float* bnp   = partials + (size_t)NBLK * 128; // 3*128
    float* kg    = bnp + 384;                     // 512
    float* coeffs = kg + 512;                     // 160
    unsigned int* ghist = (unsigned int*)(coeffs + 160);   // 8*256
    unsigned int* pfx   = ghist + 2048;                    // 8
    int* rem            = (int*)(pfx + 8);                 // 8
    int* blocktie       = rem + 8;                         // 8*49
    float* outp = (float*)d_out;

    prep_kernel<<<1, 256, 0, stream>>>(w_in, b_in, imp_w1, imp_b1, fin_w, fin_b,
                                       coeffs, ghist, pfx, rem);
    imp_kernel<<<NPIX / 256, 256, 0, stream>>>(x, coeffs, imp_w2, imp_b2, imp);

    for (int shift = 24; shift >= 0; shift -= 8) {
        topk_hist<<<BATCH * NCHUNK, 256, 0, stream>>>(imp, pfx, ghist, shift);
        topk_select<<<BATCH, 256, 0, stream>>>(ghist, pfx, rem, shift);
    }
    topk_mask1<<<BATCH * NCHUNK, 256, 0, stream>>>(imp, pfx, mask, blocktie);
    topk_mask2<<<BATCH, 256, 0, stream>>>(imp, pfx, rem, blocktie, mask);

    level0_kernel<<<NBLK, 256, 0, stream>>>(x, mask, w_in, b_in, dw0, pw0_w, pw0_b,
                                            y0, partials);
    bnfin_kernel<<<64, 256, 0, stream>>>(partials, bn0_g, bn0_b, bnp);

    dw_kernel<5, 2><<<NDWBLK, 256, 0, stream>>>(y0, bnp, dw1, yt);
    pw_kernel<<<NBLK, 256, 0, stream>>>(pw1_w, pw1_b, yt, y1, partials);
    bnfin_kernel<<<64, 256, 0, stream>>>(partials, bn1_g, bn1_b, bnp + 128);

    dw_kernel<7, 4><<<NDWBLK, 256, 0, stream>>>(y1, bnp + 128, dw2, yt);
    pw_kernel<<<NBLK, 256, 0, stream>>>(pw2_w, pw2_b, yt, y2, partials);
    bnfin_kernel<<<64, 256, 0, stream>>>(partials, bn2_g, bn2_b, bnp + 256);

    kglobal_kernel<<<512, 1024, 0, stream>>>(y2, bnp + 256, kg);
    final_kernel<<<NBLK, 256, 0, stream>>>(x, w_in, b_in, y0, y1, y2, bnp, kg,
                                           val_w, val_b, out_w, out_b, coeffs, outp);
}

// Round 17
// 385.700 us; speedup vs baseline: 1.0168x; 1.0168x over previous
//
#include <hip/hip_runtime.h>

#define HDIM 224
#define WDIM 224
#define PPIX 50176      // 224*224
#define BATCH 8
#define NPIX 401408     // 8*50176
#define KTOP 15052      // max(int(0.3*224*224), 64)
#define NELEM 25690112  // 8*64*50176
#define NBLK 6272       // 8*784 strip grid
#define NBAND2 7        // 224/32
#define NDWBLK2 3584    // 8*64*7
#define NCHUNK 49       // PPIX / 1024

typedef __attribute__((ext_vector_type(8))) short bf8_t;
typedef __attribute__((ext_vector_type(4))) float f4_t;
typedef __attribute__((ext_vector_type(8))) unsigned short us8_t;
typedef __attribute__((ext_vector_type(4))) unsigned short us4_t;
#define MFMA_BF16 __builtin_amdgcn_mfma_f32_16x16x32_bf16

// round-to-nearest-even f32 -> bf16
__device__ inline unsigned short f2bf(float f) {
    unsigned int u = __float_as_uint(f);
    return (unsigned short)((u + 0x7FFFu + ((u >> 16) & 1u)) >> 16);
}
__device__ inline float bf2f(unsigned short u) {
    return __uint_as_float(((unsigned int)u) << 16);
}

// LDS 64x64 bf16 matrix: 128B rows = 8 chunks(16B); physical chunk = k ^ g(r),
// g(r) = (r ^ (r>>3)) & 7. All fragment reads / staged writes are bank-uniform.
__device__ inline int ldsg(int r) { return ((r >> 3) ^ r) & 7; }

// stage a 64x64 fp32 matrix into swizzled bf16 LDS. 256 threads.
__device__ inline void stage_w64(const float* __restrict__ W, char* sWc, int t) {
    int o = t >> 2, cq = t & 3, c0 = cq * 16;
    const float4* src = (const float4*)(W + o * 64 + c0);
    float4 v0 = src[0], v1 = src[1], v2 = src[2], v3 = src[3];
    bf8_t p0, p1;
    p0[0] = (short)f2bf(v0.x); p0[1] = (short)f2bf(v0.y);
    p0[2] = (short)f2bf(v0.z); p0[3] = (short)f2bf(v0.w);
    p0[4] = (short)f2bf(v1.x); p0[5] = (short)f2bf(v1.y);
    p0[6] = (short)f2bf(v1.z); p0[7] = (short)f2bf(v1.w);
    p1[0] = (short)f2bf(v2.x); p1[1] = (short)f2bf(v2.y);
    p1[2] = (short)f2bf(v2.z); p1[3] = (short)f2bf(v2.w);
    p1[4] = (short)f2bf(v3.x); p1[5] = (short)f2bf(v3.y);
    p1[6] = (short)f2bf(v3.z); p1[7] = (short)f2bf(v3.w);
    int g = ldsg(o);
    *(bf8_t*)(sWc + o * 128 + (((2 * cq) ^ g) << 4)) = p0;
    *(bf8_t*)(sWc + o * 128 + (((2 * cq + 1) ^ g) << 4)) = p1;
}

// C[64o x 64p] = W(64x64, sWc) @ P([p][c], sPc); wave owns rows m0..m0+15.
__device__ inline void mfma64(const char* sWc, const char* sPc, int l, int m0, f4_t acc[4]) {
    int lr = l & 15, lg = l >> 4;
    int ra = m0 + lr, ga = ldsg(ra);
    const char* abase = sWc + ra * 128;
    bf8_t a0 = *(const bf8_t*)(abase + ((lg ^ ga) << 4));
    bf8_t a1 = *(const bf8_t*)(abase + (((lg + 4) ^ ga) << 4));
    #pragma unroll
    for (int nt = 0; nt < 4; nt++) {
        int rb = nt * 16 + lr, gb = ldsg(rb);
        const char* bbase = sPc + rb * 128;
        bf8_t b0 = *(const bf8_t*)(bbase + ((lg ^ gb) << 4));
        bf8_t b1 = *(const bf8_t*)(bbase + (((lg + 4) ^ gb) << 4));
        f4_t c = {0.f, 0.f, 0.f, 0.f};
        c = MFMA_BF16(a0, b0, c, 0, 0, 0);
        c = MFMA_BF16(a1, b1, c, 0, 0, 0);
        acc[nt] = c;
    }
}

// ---------------- prep: tiny derived coefficients + topk state init ----------
__global__ __launch_bounds__(256) void prep_kernel(
    const float* __restrict__ w_in, const float* __restrict__ b_in,
    const float* __restrict__ imp_w1, const float* __restrict__ imp_b1,
    const float* __restrict__ fin_w, const float* __restrict__ fin_b,
    float* __restrict__ coeffs, unsigned int* __restrict__ ghist,
    unsigned int* __restrict__ pfx, int* __restrict__ rem)
{
    int t = threadIdx.x;
    if (t < 16) {
        float a = 0.f, d = 0.f;
        for (int c = 0; c < 64; c++) {
            a += imp_w1[t * 64 + c] * w_in[64 + c];
            d += imp_w1[t * 64 + c] * b_in[64 + c];
        }
        coeffs[t] = a;
        coeffs[16 + t] = d + imp_b1[t];
    }
    if (t < 64) {
        float a = 0.f, d = 0.f;
        for (int c = 0; c < 64; c++) {
            a += fin_w[t * 64 + c] * w_in[c];
            d += fin_w[t * 64 + c] * b_in[c];
        }
        coeffs[32 + t] = a;
        coeffs[96 + t] = d + fin_b[t];
    }
    for (int i = t; i < 2048; i += 256) ghist[i] = 0u;
    if (t < BATCH) { pfx[t] = 0u; rem[t] = KTOP; }
}

// ---------------- importance map: sigmoid(conv3x3(relu(x*a+d), w2)+b2) --------
__global__ __launch_bounds__(256) void imp_kernel(
    const float* __restrict__ x, const float* __restrict__ coeffs,
    const float* __restrict__ imp_w2, const float* __restrict__ imp_b2,
    float* __restrict__ imp)
{
    int idx = blockIdx.x * 256 + threadIdx.x;
    int b = idx / PPIX, p = idx % PPIX;
    int h = p / WDIM, w = p % WDIM;
    float acc = imp_b2[0];
    #pragma unroll
    for (int ky = 0; ky < 3; ky++) {
        int hh = h + ky - 1;
        float okh = (hh >= 0 && hh < HDIM) ? 1.f : 0.f;
        int hc = min(max(hh, 0), HDIM - 1);
        #pragma unroll
        for (int kx = 0; kx < 3; kx++) {
            int ww = w + kx - 1;
            float ok = okh * ((ww >= 0 && ww < WDIM) ? 1.f : 0.f);
            int wc = min(max(ww, 0), WDIM - 1);
            float xv = x[b * PPIX + hc * WDIM + wc] * ok;
            #pragma unroll
            for (int c = 0; c < 16; c++) {
                float r = fmaxf(xv * coeffs[c] + coeffs[16 + c] * ok, 0.f);
                acc += r * imp_w2[c * 9 + ky * 3 + kx];
            }
        }
    }
    imp[idx] = 1.f / (1.f + expf(-acc));
}

// ---------------- parallel exact top-k: radix histogram pass ------------------
__global__ __launch_bounds__(256) void topk_hist(
    const float* __restrict__ imp, const unsigned int* __restrict__ pfx,
    unsigned int* __restrict__ ghist, int shift)
{
    int b = blockIdx.x / NCHUNK, ch = blockIdx.x % NCHUNK;
    int t = threadIdx.x;
    __shared__ unsigned int hist[256];
    hist[t] = 0u;
    __syncthreads();
    unsigned int prefix = pfx[b];
    unsigned int himask = (shift == 24) ? 0u : (0xFFFFFFFFu << (shift + 8));
    float4 v = ((const float4*)(imp + b * PPIX + ch * 1024))[t];
    unsigned int bb[4] = {__float_as_uint(v.x), __float_as_uint(v.y),
                          __float_as_uint(v.z), __float_as_uint(v.w)};
    #pragma unroll
    for (int k = 0; k < 4; k++)
        if ((bb[k] & himask) == prefix)
            atomicAdd(&hist[(bb[k] >> shift) & 255u], 1u);
    __syncthreads();
    unsigned int c = hist[t];
    if (c) atomicAdd(&ghist[b * 256 + t], c);
}

// ---------------- top-k: select bin, update prefix/remaining, zero hist -------
__global__ __launch_bounds__(256) void topk_select(
    unsigned int* __restrict__ ghist, unsigned int* __restrict__ pfx,
    int* __restrict__ rem, int shift)
{
    int b = blockIdx.x;
    int t = threadIdx.x;
    __shared__ unsigned int h[256];
    h[t] = ghist[b * 256 + t];
    ghist[b * 256 + t] = 0u;
    __syncthreads();
    if (t == 0) {
        int r = rem[b];
        unsigned int bsel = 0u;
        for (int bin = 255; bin >= 0; bin--) {
            int c = (int)h[bin];
            if (c >= r) { bsel = (unsigned int)bin; break; }
            r -= c;
        }
        rem[b] = r;
        pfx[b] |= bsel << shift;
    }
}

// ---------------- top-k: write mask for >T, count ties per chunk --------------
__global__ __launch_bounds__(256) void topk_mask1(
    const float* __restrict__ imp, const unsigned int* __restrict__ pfx,
    float* __restrict__ mask, int* __restrict__ blocktie)
{
    int b = blockIdx.x / NCHUNK, ch = blockIdx.x % NCHUNK;
    int t = threadIdx.x;
    unsigned int T = pfx[b];
    float4 v = ((const float4*)(imp + b * PPIX + ch * 1024))[t];
    unsigned int bb[4] = {__float_as_uint(v.x), __float_as_uint(v.y),
                          __float_as_uint(v.z), __float_as_uint(v.w)};
    float4 mo;
    float* mp = &mo.x;
    int cnt = 0;
    #pragma unroll
    for (int k = 0; k < 4; k++) {
        mp[k] = (bb[k] > T) ? 1.f : 0.f;
        cnt += (bb[k] == T) ? 1 : 0;
    }
    ((float4*)(mask + b * PPIX + ch * 1024))[t] = mo;
    #pragma unroll
    for (int off = 32; off > 0; off >>= 1) cnt += __shfl_down(cnt, off);
    __shared__ int ws4[4];
    int lane = t & 63, wv = t >> 6;
    if (lane == 0) ws4[wv] = cnt;
    __syncthreads();
    if (t == 0) blocktie[b * NCHUNK + ch] = ws4[0] + ws4[1] + ws4[2] + ws4[3];
}

// ---------------- top-k: set first `rem` ties in index order ------------------
__global__ __launch_bounds__(256) void topk_mask2(
    const float* __restrict__ imp, const unsigned int* __restrict__ pfx,
    const int* __restrict__ rem_, const int* __restrict__ blocktie,
    float* __restrict__ mask)
{
    int b = blockIdx.x;
    int t = threadIdx.x, lane = t & 63, wv = t >> 6;
    unsigned int T = pfx[b];
    int rem = rem_[b];
    __shared__ int sbase[NCHUNK], scnt[NCHUNK];
    if (t == 0) {
        int s = 0;
        for (int i = 0; i < NCHUNK; i++) {
            sbase[i] = s;
            int c = blocktie[b * NCHUNK + i];
            scnt[i] = c;
            s += c;
        }
    }
    __syncthreads();
    __shared__ int wtot[4];
    for (int ch = 0; ch < NCHUNK; ch++) {
        if (scnt[ch] == 0) continue;
        int base = sbase[ch];
        if (base >= rem) break;
        for (int g = 0; g < 4; g++) {
            int i = b * PPIX + ch * 1024 + g * 256 + t;
            int flag = (__float_as_uint(imp[i]) == T) ? 1 : 0;
            unsigned long long bal = __ballot(flag);
            if (lane == 0) wtot[wv] = __popcll(bal);
            __syncthreads();
            int wbase = 0, tot = 0;
            for (int q = 0; q < 4; q++) { int c = wtot[q]; if (q < wv) wbase += c; tot += c; }
            if (flag && base + wbase + __popcll(bal & ((1ull << lane) - 1ull)) < rem)
                mask[i] = 1.f;
            base += tot;
            __syncthreads();
        }
    }
}

// ---------------- level 0: masked dwconv3x3 -> MFMA 1x1, y0(bf16) + partials --
__global__ __launch_bounds__(256, 4) void level0_kernel(
    const float* __restrict__ x, const float* __restrict__ mask,
    const float* __restrict__ w_in, const float* __restrict__ b_in,
    const float* __restrict__ dw_w, const float* __restrict__ pw_w,
    const float* __restrict__ pw_b,
    unsigned short* __restrict__ y_out, float* __restrict__ partials)
{
    __shared__ __align__(16) short sW[4096];
    __shared__ __align__(16) short sP[4096];
    __shared__ float sred[128];
    __shared__ float sBias[64];
    char* sWc = (char*)sW; char* sPc = (char*)sP;
    int t = threadIdx.x;
    int swz = (blockIdx.x & 7) * 784 + (blockIdx.x >> 3);
    int b = swz / 784;
    int l = t & 63, og = t >> 6;
    int p0 = (swz % 784) * 64;
    int p = p0 + l;
    int h = p / WDIM, w = p % WDIM;
    stage_w64(pw_w, sWc, t);
    if (t < 64) sBias[t] = pw_b[t];

    int rowoff[3]; float okhf[3];
    int wcs[3]; float okwf[3];
    #pragma unroll
    for (int k = 0; k < 3; k++) {
        int hh = h + k - 1;
        okhf[k] = (hh >= 0 && hh < HDIM) ? 1.f : 0.f;
        rowoff[k] = min(max(hh, 0), HDIM - 1) * WDIM;
        int ww = w + k - 1;
        okwf[k] = (ww >= 0 && ww < WDIM) ? 1.f : 0.f;
        wcs[k] = min(max(ww, 0), WDIM - 1);
    }
    float mv[9], mxv[9];
    const float* mb = mask + b * PPIX;
    const float* xb = x + b * PPIX;
    #pragma unroll
    for (int ky = 0; ky < 3; ky++) {
        #pragma unroll
        for (int kx = 0; kx < 3; kx++) {
            int a = rowoff[ky] + wcs[kx];
            float mm = mb[a] * (okhf[ky] * okwf[kx]);
            mv[ky * 3 + kx] = mm;
            mxv[ky * 3 + kx] = mm * xb[a];
        }
    }
    bf8_t pk0, pk1;
    #pragma unroll
    for (int j = 0; j < 16; j++) {
        int c = og * 16 + j;
        float wk = w_in[64 + c], bk = b_in[64 + c];
        const float* dwr = dw_w + c * 9;
        float a0 = 0.f, a1 = 0.f;
        #pragma unroll
        for (int tp = 0; tp < 9; tp++) {
            float dv = dwr[tp];
            a0 += dv * mxv[tp];
            a1 += dv * mv[tp];
        }
        unsigned short bv = f2bf(wk * a0 + bk * a1);
        if (j < 8) pk0[j] = (short)bv; else pk1[j - 8] = (short)bv;
    }
    int gl = ldsg(l);
    *(bf8_t*)(sPc + l * 128 + (((2 * og) ^ gl) << 4)) = pk0;
    *(bf8_t*)(sPc + l * 128 + (((2 * og + 1) ^ gl) << 4)) = pk1;
    __syncthreads();

    int m0 = og * 16, lr = l & 15, lg = l >> 4;
    f4_t acc[4];
    mfma64(sWc, sPc, l, m0, acc);
    unsigned short* ybase = y_out + (size_t)b * 64 * PPIX + p0;
    #pragma unroll
    for (int r = 0; r < 4; r++) {
        int o = m0 + 4 * lg + r;
        float bias = sBias[o];
        float s = 0.f, s2 = 0.f;
        #pragma unroll
        for (int nt = 0; nt < 4; nt++) {
            float yv = acc[nt][r] + bias;
            ybase[(size_t)o * PPIX + nt * 16 + lr] = f2bf(yv);
            s += yv; s2 += yv * yv;
        }
        #pragma unroll
        for (int m = 1; m < 16; m <<= 1) {
            s += __shfl_xor(s, m);
            s2 += __shfl_xor(s2, m);
        }
        if (lr == 0) { sred[2 * o] = s; sred[2 * o + 1] = s2; }
    }
    __syncthreads();
    if (t < 128) partials[(size_t)blockIdx.x * 128 + t] = sred[t];
}

// ---------------- dilated dwconv: paired-row register reuse, BH=32 ------------
// thread computes output rows (g, g+DIL): KSZ+1 shared segments serve both
// rows -> LDS reads drop from KSZ*SEG to (KSZ+1)*SEG per 2 rows (-43%).
// lane map pg-fastest: rows vary across lanes -> b128 reads spread all quads.
template<int KSZ, int DIL, int OCC>
__global__ __launch_bounds__(256, OCC) void dw_kernel(
    const unsigned short* __restrict__ in, const float* __restrict__ bnp,
    const float* __restrict__ dw_w, unsigned short* __restrict__ out)
{
    constexpr int PAD = (KSZ / 2) * DIL;
    constexpr int BH = 32;
    constexpr int LR = BH + 2 * PAD;          // 56 (7,4) / 40 (5,2)
    constexpr int SW = WDIM + 2 * PAD + 4;    // 252 / 236
    constexpr int SEG = 16 + 2 * PAD;         // 40 / 24
    __shared__ float sIn[LR * SW];

    int t = threadIdx.x;
    int swz = (blockIdx.x & 7) * (NDWBLK2 / 8) + (blockIdx.x >> 3);
    int bc = swz / NBAND2, band = swz % NBAND2;
    int c = bc & 63;
    int r0 = band * BH;
    float sc = bnp[c], sh = bnp[64 + c];
    const unsigned short* plane = in + (size_t)bc * PPIX;

    constexpr int PADC = SW - WDIM;
    for (int i = t; i < LR * PADC; i += 256) {
        int r = i / PADC, cc = i % PADC;
        int col = (cc < PAD) ? cc : (cc + WDIM);
        sIn[r * SW + col] = 0.f;
    }
    for (int i = t; i < LR * 28; i += 256) {
        int sr = i / 28, q = i % 28;
        int gr = r0 - PAD + sr;
        float4 a = {0.f, 0.f, 0.f, 0.f}, bq = {0.f, 0.f, 0.f, 0.f};
        if (gr >= 0 && gr < HDIM) {
            us8_t v = *(const us8_t*)(plane + gr * WDIM + 8 * q);
            a.x = fmaxf(sc * bf2f(v[0]) + sh, 0.f);
            a.y = fmaxf(sc * bf2f(v[1]) + sh, 0.f);
            a.z = fmaxf(sc * bf2f(v[2]) + sh, 0.f);
            a.w = fmaxf(sc * bf2f(v[3]) + sh, 0.f);
            bq.x = fmaxf(sc * bf2f(v[4]) + sh, 0.f);
            bq.y = fmaxf(sc * bf2f(v[5]) + sh, 0.f);
            bq.z = fmaxf(sc * bf2f(v[6]) + sh, 0.f);
            bq.w = fmaxf(sc * bf2f(v[7]) + sh, 0.f);
        }
        *(float4*)(sIn + sr * SW + PAD + 8 * q) = a;
        *(float4*)(sIn + sr * SW + PAD + 8 * q + 4) = bq;
    }
    __syncthreads();

    if (t < 224) {   // no barriers below; idle tail predicated
        const float* dwr = dw_w + c * KSZ * KSZ;
        float wk[KSZ * KSZ];
        #pragma unroll
        for (int i = 0; i < KSZ * KSZ; i++) wk[i] = dwr[i];

        int pg = t & 15, xs = t >> 4;        // pg-fastest: rows vary per lane
        int g = (pg % DIL) + 2 * DIL * (pg / DIL);   // pairs (g, g+DIL)
        int x0 = xs * 16;
        float a0[16], a1[16];
        #pragma unroll
        for (int j = 0; j < 16; j++) { a0[j] = 0.f; a1[j] = 0.f; }
        #pragma unroll
        for (int s = 0; s <= KSZ; s++) {
            const float4* srow = (const float4*)(sIn + (g + DIL * s) * SW + x0);
            float sv[SEG];
            #pragma unroll
            for (int i = 0; i < SEG / 4; i++) ((float4*)sv)[i] = srow[i];
            if (s < KSZ) {
                #pragma unroll
                for (int kx = 0; kx < KSZ; kx++) {
                    float wv = wk[s * KSZ + kx];
                    #pragma unroll
                    for (int j = 0; j < 16; j++)
                        a0[j] += sv[j + DIL * kx] * wv;
                }
            }
            if (s >= 1) {
                #pragma unroll
                for (int kx = 0; kx < KSZ; kx++) {
                    float wv = wk[(s - 1) * KSZ + kx];
                    #pragma unroll
                    for (int j = 0; j < 16; j++)
                        a1[j] += sv[j + DIL * kx] * wv;
                }
            }
        }
        us8_t o00, o01, o10, o11;
        #pragma unroll
        for (int j = 0; j < 8; j++) {
            o00[j] = f2bf(a0[j]); o01[j] = f2bf(a0[8 + j]);
            o10[j] = f2bf(a1[j]); o11[j] = f2bf(a1[8 + j]);
        }
        unsigned short* orow0 = out + (size_t)bc * PPIX + (r0 + g) * WDIM + x0;
        unsigned short* orow1 = orow0 + DIL * WDIM;
        *(us8_t*)orow0 = o00;
        *(us8_t*)(orow0 + 8) = o01;
        *(us8_t*)orow1 = o10;
        *(us8_t*)(orow1 + 8) = o11;
    }
}

// ---------------- pointwise 64x64 MFMA matvec, OUT-OF-PLACE, + bn partials ----
__global__ __launch_bounds__(256, 4) void pw_kernel(
    const float* __restrict__ pw_w, const float* __restrict__ pw_b,
    const unsigned short* __restrict__ src_y, unsigned short* __restrict__ dst_y,
    float* __restrict__ partials)
{
    __shared__ __align__(16) short sW[4096];
    __shared__ __align__(16) short sP[4096];
    __shared__ float sred[128];
    __shared__ float sBias[64];
    char* sWc = (char*)sW; char* sPc = (char*)sP;
    int t = threadIdx.x;
    int swz = (blockIdx.x & 7) * 784 + (blockIdx.x >> 3);
    int b = swz / 784;
    int p0 = (swz % 784) * 64;
    stage_w64(pw_w, sWc, t);
    if (t < 64) sBias[t] = pw_b[t];

    const unsigned short* sbase_g = src_y + (size_t)b * 64 * PPIX + p0;
    unsigned short* dbase_g = dst_y + (size_t)b * 64 * PPIX + p0;
    {
        int c = t >> 2, pg = t & 3;
        const unsigned short* src = sbase_g + (size_t)c * PPIX + 16 * pg;
        us8_t v0 = *(const us8_t*)src;
        us8_t v1 = *(const us8_t*)(src + 8);
        int kc = c >> 3, cb = 2 * (c & 7);
        #pragma unroll
        for (int e = 0; e < 16; e++) {
            int r = 16 * pg + e;
            int gr = ldsg(r);
            unsigned short val = (e < 8) ? (unsigned short)v0[e] : (unsigned short)v1[e - 8];
            *(unsigned short*)(sPc + r * 128 + ((kc ^ gr) << 4) + cb) = val;
        }
    }
    __syncthreads();

    int l = t & 63, wv = t >> 6, m0 = wv * 16;
    int lr = l & 15, lg = l >> 4;
    f4_t acc[4];
    mfma64(sWc, sPc, l, m0, acc);
    #pragma unroll
    for (int r = 0; r < 4; r++) {
        int o = m0 + 4 * lg + r;
        float bias = sBias[o];
        float s = 0.f, s2 = 0.f;
        #pragma unroll
        for (int nt = 0; nt < 4; nt++) {
            float yv = acc[nt][r] + bias;
            dbase_g[(size_t)o * PPIX + nt * 16 + lr] = f2bf(yv);
            s += yv; s2 += yv * yv;
        }
        #pragma unroll
        for (int m = 1; m < 16; m <<= 1) {
            s += __shfl_xor(s, m);
            s2 += __shfl_xor(s2, m);
        }
        if (lr == 0) { sred[2 * o] = s; sred[2 * o + 1] = s2; }
    }
    __syncthreads();
    if (t < 128) partials[(size_t)blockIdx.x * 128 + t] = sred[t];
}

// ---------------- bn finalize: tree-reduce partials, one block per channel ----
__global__ __launch_bounds__(256) void bnfin_kernel(
    const float* __restrict__ partials,
    const float* __restrict__ g, const float* __restrict__ be,
    float* __restrict__ bnp)
{
    int c = blockIdx.x;
    int t = threadIdx.x;
    float s = 0.f, s2 = 0.f;
    for (int blk = t; blk < NBLK; blk += 256) {
        s  += partials[(size_t)blk * 128 + 2 * c];
        s2 += partials[(size_t)blk * 128 + 2 * c + 1];
    }
    #pragma unroll
    for (int off = 32; off > 0; off >>= 1) {
        s += __shfl_down(s, off);
        s2 += __shfl_down(s2, off);
    }
    __shared__ float wsm[8];
    int lane = t & 63, wv = t >> 6;
    if (lane == 0) { wsm[wv] = s; wsm[4 + wv] = s2; }
    __syncthreads();
    if (t == 0) {
        s = wsm[0] + wsm[1] + wsm[2] + wsm[3];
        s2 = wsm[4] + wsm[5] + wsm[6] + wsm[7];
        const float inv_n = 1.f / (float)NPIX;
        float mu = s * inv_n;
        float var = s2 * inv_n - mu * mu;
        float sc = g[c] * rsqrtf(var + 1e-5f);
        bnp[c] = sc;
        bnp[64 + c] = be[c] - mu * sc;
    }
}

// ---------------- K_global: per (b,c) spatial mean of relu(bn(y2)) ------------
__global__ __launch_bounds__(1024) void kglobal_kernel(
    const unsigned short* __restrict__ y2, const float* __restrict__ bnp2,
    float* __restrict__ kg)
{
    int bc = blockIdx.x;
    int c = bc & 63;
    int t = threadIdx.x;
    const unsigned short* row = y2 + (size_t)bc * PPIX;
    float sc = bnp2[c], sh = bnp2[64 + c];
    float s = 0.f;
    for (int ii = t; ii < PPIX / 8; ii += 1024) {
        us8_t v = *(const us8_t*)(row + 8 * ii);
        #pragma unroll
        for (int k = 0; k < 8; k++) s += fmaxf(sc * bf2f(v[k]) + sh, 0.f);
    }
    #pragma unroll
    for (int off = 32; off > 0; off >>= 1) s += __shfl_down(s, off);
    __shared__ float wsum[16];
    int lane = t & 63, wv = t >> 6;
    if (lane == 0) wsum[wv] = s;
    __syncthreads();
    if (t == 0) {
        float tot = 0.f;
        #pragma unroll
        for (int q = 0; q < 16; q++) tot += wsum[q];
        kg[bc] = tot * (1.f / (float)PPIX);
    }
}

// ---------------- final: aggregate + MFMA V + QV + MFMA O + x_proj ------------
__global__ __launch_bounds__(256, 4) void final_kernel(
    const float* __restrict__ x, const float* __restrict__ w_in,
    const float* __restrict__ b_in,
    const unsigned short* __restrict__ y0, const unsigned short* __restrict__ y1,
    const unsigned short* __restrict__ y2,
    const float* __restrict__ bnp, const float* __restrict__ kg,
    const float* __restrict__ val_w, const float* __restrict__ val_b,
    const float* __restrict__ out_w, const float* __restrict__ out_b,
    const float* __restrict__ coeffs, float* __restrict__ out)
{
    __shared__ __align__(16) short sVW[4096];
    __shared__ __align__(16) short sOW[4096];
    __shared__ __align__(16) short sP[4096];
    __shared__ float sxv[64], sG[320];   // sG stride-5: 2-way max bank alias
    __shared__ float sQW[64], sQB[64], sVB[64], sOB[64], sC1[64], sC2[64];
    char* sVWc = (char*)sVW; char* sOWc = (char*)sOW; char* sPc = (char*)sP;
    int t = threadIdx.x;
    int blk = blockIdx.x;
    int b = blk / 784;
    int l = t & 63, wv = t >> 6;
    int p0 = (blk % 784) * 64;
    stage_w64(val_w, sVWc, t);
    stage_w64(out_w, sOWc, t);
    if (t < 64) {
        sQW[t] = w_in[t]; sQB[t] = b_in[t];
        sVB[t] = val_b[t]; sOB[t] = out_b[t];
        sC1[t] = coeffs[32 + t]; sC2[t] = coeffs[96 + t];
        float xv = x[b * PPIX + p0 + t];
        sxv[t] = xv;
        float g0 = xv * w_in[128] + b_in[128];
        float g1 = xv * w_in[129] + b_in[129];
        float g2 = xv * w_in[130] + b_in[130];
        float g3 = xv * w_in[131] + b_in[131];
        float mx = fmaxf(fmaxf(g0, g1), fmaxf(g2, g3));
        float e0 = expf(g0 - mx), e1 = expf(g1 - mx);
        float e2 = expf(g2 - mx), e3 = expf(g3 - mx);
        float inv = 1.f / (e0 + e1 + e2 + e3);
        sG[5 * t + 0] = e0 * inv;
        sG[5 * t + 1] = e1 * inv;
        sG[5 * t + 2] = e2 * inv;
        sG[5 * t + 3] = e3 * inv;
    }
    __syncthreads();

    // P staging: thread = (channel c, 16-pixel group pg), us8 vector loads
    {
        int c = t >> 2, pg = t & 3;
        size_t base = (size_t)(b * 64 + c) * PPIX + p0 + 16 * pg;
        us8_t a0 = *(const us8_t*)(y0 + base);
        us8_t a1 = *(const us8_t*)(y0 + base + 8);
        us8_t q0 = *(const us8_t*)(y1 + base);
        us8_t q1 = *(const us8_t*)(y1 + base + 8);
        us8_t r0 = *(const us8_t*)(y2 + base);
        us8_t r1 = *(const us8_t*)(y2 + base + 8);
        float s0 = bnp[c],       h0 = bnp[64 + c];
        float s1 = bnp[128 + c], h1 = bnp[192 + c];
        float s2 = bnp[256 + c], h2 = bnp[320 + c];
        float kgc = kg[b * 64 + c];
        int kc = c >> 3, cb = 2 * (c & 7);
        #pragma unroll
        for (int e = 0; e < 16; e++) {
            unsigned short u0 = (e < 8) ? (unsigned short)a0[e] : (unsigned short)a1[e - 8];
            unsigned short u1 = (e < 8) ? (unsigned short)q0[e] : (unsigned short)q1[e - 8];
            unsigned short u2 = (e < 8) ? (unsigned short)r0[e] : (unsigned short)r1[e - 8];
            float f0 = fmaxf(s0 * bf2f(u0) + h0, 0.f);
            float f1 = fmaxf(s1 * bf2f(u1) + h1, 0.f);
            float f2 = fmaxf(s2 * bf2f(u2) + h2, 0.f);
            int r = 16 * pg + e;
            float kf = sG[5 * r] * f0 + sG[5 * r + 1] * f1
                     + sG[5 * r + 2] * f2 + sG[5 * r + 3] * kgc;
            int gr = ldsg(r);
            *(unsigned short*)(sPc + r * 128 + ((kc ^ gr) << 4) + cb) = f2bf(kf);
        }
    }
    __syncthreads();

    int m0 = wv * 16, lr = l & 15, lg = l >> 4;
    f4_t accV[4];
    mfma64(sVWc, sPc, l, m0, accV);
    __syncthreads();   // all P reads done before QV overwrite

    #pragma unroll
    for (int nt = 0; nt < 4; nt++) {
        float xvp = sxv[nt * 16 + lr];
        us4_t q4;
        #pragma unroll
        for (int r = 0; r < 4; r++) {
            int o = m0 + 4 * lg + r;
            float V = accV[nt][r] + sVB[o];
            float q = xvp * sQW[o] + sQB[o];
            q4[r] = f2bf(q * V);
        }
        int rb = nt * 16 + lr, gb = ldsg(rb);
        int kc = 2 * wv + (lg >> 1);
        *(us4_t*)(sPc + rb * 128 + ((kc ^ gb) << 4) + 8 * (lg & 1)) = q4;
    }
    __syncthreads();

    f4_t accO[4];
    mfma64(sOWc, sPc, l, m0, accO);
    #pragma unroll
    for (int nt = 0; nt < 4; nt++) {
        float xvp = sxv[nt * 16 + lr];
        #pragma unroll
        for (int r = 0; r < 4; r++) {
            int o = m0 + 4 * lg + r;
            out[(size_t)(b * 64 + o) * PPIX + p0 + nt * 16 + lr] =
                accO[nt][r] + sOB[o] + xvp * sC1[o] + sC2[o];
        }
    }
}

extern "C" void kernel_launch(void* const* d_in, const int* in_sizes, int n_in,
                              void* d_out, int out_size, void* d_ws, size_t ws_size,
                              hipStream_t stream)
{
    (void)in_sizes; (void)n_in; (void)out_size; (void)ws_size;
    const float* x      = (const float*)d_in[0];
    const float* w_in   = (const float*)d_in[1];
    const float* b_in   = (const float*)d_in[2];
    const float* dw0    = (const float*)d_in[3];
    const float* pw0_w  = (const float*)d_in[4];
    const float* pw0_b  = (const float*)d_in[5];
    const float* bn0_g  = (const float*)d_in[6];
    const float* bn0_b  = (const float*)d_in[7];
    const float* dw1    = (const float*)d_in[8];
    const float* pw1_w  = (const float*)d_in[9];
    const float* pw1_b  = (const float*)d_in[10];
    const float* bn1_g  = (const float*)d_in[11];
    const float* bn1_b  = (const float*)d_in[12];
    const float* dw2    = (const float*)d_in[13];
    const float* pw2_w  = (const float*)d_in[14];
    const float* pw2_b  = (const float*)d_in[15];
    const float* bn2_g  = (const float*)d_in[16];
    const float* bn2_b  = (const float*)d_in[17];
    const float* imp_w1 = (const float*)d_in[18];
    const float* imp_b1 = (const float*)d_in[19];
    const float* imp_w2 = (const float*)d_in[20];
    const float* imp_b2 = (const float*)d_in[21];
    const float* val_w  = (const float*)d_in[22];
    const float* val_b  = (const float*)d_in[23];
    const float* out_w  = (const float*)d_in[24];
    const float* out_b  = (const float*)d_in[25];
    const float* fin_w  = (const float*)d_in[26];
    const float* fin_b  = (const float*)d_in[27];

    unsigned short* y0 = (unsigned short*)d_ws;
    unsigned short* y1 = y0 + (size_t)NELEM;
    unsigned short* y2 = y1 + (size_t)NELEM;
    unsigned short* yt = y2 + (size_t)NELEM;           // dwconv temp
    float* imp  = (float*)(yt + (size_t)NELEM);
    float* mask = imp + NPIX;
    float* partials = mask + NPIX;                // 6272*128
    float* bnp   = partials + (size_t)NBLK * 128; // 3*128
    float* kg    = bnp + 384;                     // 512
    float* coeffs = kg + 512;                     // 160
    unsigned int* ghist = (unsigned int*)(coeffs + 160);   // 8*256
    unsigned int* pfx   = ghist + 2048;                    // 8
    int* rem            = (int*)(pfx + 8);                 // 8
    int* blocktie       = rem + 8;                         // 8*49
    float* outp = (float*)d_out;

    prep_kernel<<<1, 256, 0, stream>>>(w_in, b_in, imp_w1, imp_b1, fin_w, fin_b,
                                       coeffs, ghist, pfx, rem);
    imp_kernel<<<NPIX / 256, 256, 0, stream>>>(x, coeffs, imp_w2, imp_b2, imp);

    for (int shift = 24; shift >= 0; shift -= 8) {
        topk_hist<<<BATCH * NCHUNK, 256, 0, stream>>>(imp, pfx, ghist, shift);
        topk_select<<<BATCH, 256, 0, stream>>>(ghist, pfx, rem, shift);
    }
    topk_mask1<<<BATCH * NCHUNK, 256, 0, stream>>>(imp, pfx, mask, blocktie);
    topk_mask2<<<BATCH, 256, 0, stream>>>(imp, pfx, rem, blocktie, mask);

    level0_kernel<<<NBLK, 256, 0, stream>>>(x, mask, w_in, b_in, dw0, pw0_w, pw0_b,
                                            y0, partials);
    bnfin_kernel<<<64, 256, 0, stream>>>(partials, bn0_g, bn0_b, bnp);

    dw_kernel<5, 2, 4><<<NDWBLK2, 256, 0, stream>>>(y0, bnp, dw1, yt);
    pw_kernel<<<NBLK, 256, 0, stream>>>(pw1_w, pw1_b, yt, y1, partials);
    bnfin_kernel<<<64, 256, 0, stream>>>(partials, bn1_g, bn1_b, bnp + 128);

    dw_kernel<7, 4, 2><<<NDWBLK2, 256, 0, stream>>>(y1, bnp + 128, dw2, yt);
    pw_kernel<<<NBLK, 256, 0, stream>>>(pw2_w, pw2_b, yt, y2, partials);
    bnfin_kernel<<<64, 256, 0, stream>>>(partials, bn2_g, bn2_b, bnp + 256);

    kglobal_kernel<<<512, 1024, 0, stream>>>(y2, bnp + 256, kg);
    final_kernel<<<NBLK, 256, 0, stream>>>(x, w_in, b_in, y0, y1, y2, bnp, kg,
                                           val_w, val_b, out_w, out_b, coeffs, outp);
}

// Round 18
// 379.825 us; speedup vs baseline: 1.0325x; 1.0155x over previous
//
#include <hip/hip_runtime.h>

#define HDIM 224
#define WDIM 224
#define PPIX 50176      // 224*224
#define BATCH 8
#define NPIX 401408     // 8*50176
#define KTOP 15052      // max(int(0.3*224*224), 64)
#define NELEM 25690112  // 8*64*50176
#define NBLK 6272       // 8*784 strip grid
#define NBAND 14        // 224/16
#define NDWBLK 7168     // 8*64*14
#define NCHUNK 49       // PPIX / 1024

typedef __attribute__((ext_vector_type(8))) short bf8_t;
typedef __attribute__((ext_vector_type(4))) float f4_t;
typedef __attribute__((ext_vector_type(8))) unsigned short us8_t;
typedef __attribute__((ext_vector_type(4))) unsigned short us4_t;
#define MFMA_BF16 __builtin_amdgcn_mfma_f32_16x16x32_bf16

// round-to-nearest-even f32 -> bf16
__device__ inline unsigned short f2bf(float f) {
    unsigned int u = __float_as_uint(f);
    return (unsigned short)((u + 0x7FFFu + ((u >> 16) & 1u)) >> 16);
}
__device__ inline float bf2f(unsigned short u) {
    return __uint_as_float(((unsigned int)u) << 16);
}

// LDS 64x64 bf16 matrix: 128B rows = 8 chunks(16B); physical chunk = k ^ g(r),
// g(r) = (r ^ (r>>3)) & 7. All fragment reads / staged writes are bank-uniform.
__device__ inline int ldsg(int r) { return ((r >> 3) ^ r) & 7; }

// stage a 64x64 fp32 matrix into swizzled bf16 LDS. 256 threads.
__device__ inline void stage_w64(const float* __restrict__ W, char* sWc, int t) {
    int o = t >> 2, cq = t & 3, c0 = cq * 16;
    const float4* src = (const float4*)(W + o * 64 + c0);
    float4 v0 = src[0], v1 = src[1], v2 = src[2], v3 = src[3];
    bf8_t p0, p1;
    p0[0] = (short)f2bf(v0.x); p0[1] = (short)f2bf(v0.y);
    p0[2] = (short)f2bf(v0.z); p0[3] = (short)f2bf(v0.w);
    p0[4] = (short)f2bf(v1.x); p0[5] = (short)f2bf(v1.y);
    p0[6] = (short)f2bf(v1.z); p0[7] = (short)f2bf(v1.w);
    p1[0] = (short)f2bf(v2.x); p1[1] = (short)f2bf(v2.y);
    p1[2] = (short)f2bf(v2.z); p1[3] = (short)f2bf(v2.w);
    p1[4] = (short)f2bf(v3.x); p1[5] = (short)f2bf(v3.y);
    p1[6] = (short)f2bf(v3.z); p1[7] = (short)f2bf(v3.w);
    int g = ldsg(o);
    *(bf8_t*)(sWc + o * 128 + (((2 * cq) ^ g) << 4)) = p0;
    *(bf8_t*)(sWc + o * 128 + (((2 * cq + 1) ^ g) << 4)) = p1;
}

// C[64o x 64p] = W(64x64, sWc) @ P([p][c], sPc); wave owns rows m0..m0+15.
__device__ inline void mfma64(const char* sWc, const char* sPc, int l, int m0, f4_t acc[4]) {
    int lr = l & 15, lg = l >> 4;
    int ra = m0 + lr, ga = ldsg(ra);
    const char* abase = sWc + ra * 128;
    bf8_t a0 = *(const bf8_t*)(abase + ((lg ^ ga) << 4));
    bf8_t a1 = *(const bf8_t*)(abase + (((lg + 4) ^ ga) << 4));
    #pragma unroll
    for (int nt = 0; nt < 4; nt++) {
        int rb = nt * 16 + lr, gb = ldsg(rb);
        const char* bbase = sPc + rb * 128;
        bf8_t b0 = *(const bf8_t*)(bbase + ((lg ^ gb) << 4));
        bf8_t b1 = *(const bf8_t*)(bbase + (((lg + 4) ^ gb) << 4));
        f4_t c = {0.f, 0.f, 0.f, 0.f};
        c = MFMA_BF16(a0, b0, c, 0, 0, 0);
        c = MFMA_BF16(a1, b1, c, 0, 0, 0);
        acc[nt] = c;
    }
}

// ---------------- prep: tiny derived coefficients + topk state init ----------
__global__ __launch_bounds__(256) void prep_kernel(
    const float* __restrict__ w_in, const float* __restrict__ b_in,
    const float* __restrict__ imp_w1, const float* __restrict__ imp_b1,
    const float* __restrict__ fin_w, const float* __restrict__ fin_b,
    float* __restrict__ coeffs, unsigned int* __restrict__ ghist,
    unsigned int* __restrict__ pfx, int* __restrict__ rem)
{
    int t = threadIdx.x;
    if (t < 16) {
        float a = 0.f, d = 0.f;
        for (int c = 0; c < 64; c++) {
            a += imp_w1[t * 64 + c] * w_in[64 + c];
            d += imp_w1[t * 64 + c] * b_in[64 + c];
        }
        coeffs[t] = a;
        coeffs[16 + t] = d + imp_b1[t];
    }
    if (t < 64) {
        float a = 0.f, d = 0.f;
        for (int c = 0; c < 64; c++) {
            a += fin_w[t * 64 + c] * w_in[c];
            d += fin_w[t * 64 + c] * b_in[c];
        }
        coeffs[32 + t] = a;
        coeffs[96 + t] = d + fin_b[t];
    }
    for (int i = t; i < 2048; i += 256) ghist[i] = 0u;
    if (t < BATCH) { pfx[t] = 0u; rem[t] = KTOP; }
}

// ---------------- importance map: sigmoid(conv3x3(relu(x*a+d), w2)+b2) --------
__global__ __launch_bounds__(256) void imp_kernel(
    const float* __restrict__ x, const float* __restrict__ coeffs,
    const float* __restrict__ imp_w2, const float* __restrict__ imp_b2,
    float* __restrict__ imp)
{
    int idx = blockIdx.x * 256 + threadIdx.x;
    int b = idx / PPIX, p = idx % PPIX;
    int h = p / WDIM, w = p % WDIM;
    float acc = imp_b2[0];
    #pragma unroll
    for (int ky = 0; ky < 3; ky++) {
        int hh = h + ky - 1;
        float okh = (hh >= 0 && hh < HDIM) ? 1.f : 0.f;
        int hc = min(max(hh, 0), HDIM - 1);
        #pragma unroll
        for (int kx = 0; kx < 3; kx++) {
            int ww = w + kx - 1;
            float ok = okh * ((ww >= 0 && ww < WDIM) ? 1.f : 0.f);
            int wc = min(max(ww, 0), WDIM - 1);
            float xv = x[b * PPIX + hc * WDIM + wc] * ok;
            #pragma unroll
            for (int c = 0; c < 16; c++) {
                float r = fmaxf(xv * coeffs[c] + coeffs[16 + c] * ok, 0.f);
                acc += r * imp_w2[c * 9 + ky * 3 + kx];
            }
        }
    }
    imp[idx] = 1.f / (1.f + expf(-acc));
}

// ---------------- parallel exact top-k: radix histogram pass ------------------
__global__ __launch_bounds__(256) void topk_hist(
    const float* __restrict__ imp, const unsigned int* __restrict__ pfx,
    unsigned int* __restrict__ ghist, int shift)
{
    int b = blockIdx.x / NCHUNK, ch = blockIdx.x % NCHUNK;
    int t = threadIdx.x;
    __shared__ unsigned int hist[256];
    hist[t] = 0u;
    __syncthreads();
    unsigned int prefix = pfx[b];
    unsigned int himask = (shift == 24) ? 0u : (0xFFFFFFFFu << (shift + 8));
    float4 v = ((const float4*)(imp + b * PPIX + ch * 1024))[t];
    unsigned int bb[4] = {__float_as_uint(v.x), __float_as_uint(v.y),
                          __float_as_uint(v.z), __float_as_uint(v.w)};
    #pragma unroll
    for (int k = 0; k < 4; k++)
        if ((bb[k] & himask) == prefix)
            atomicAdd(&hist[(bb[k] >> shift) & 255u], 1u);
    __syncthreads();
    unsigned int c = hist[t];
    if (c) atomicAdd(&ghist[b * 256 + t], c);
}

// ---------------- top-k: select bin, update prefix/remaining, zero hist -------
__global__ __launch_bounds__(256) void topk_select(
    unsigned int* __restrict__ ghist, unsigned int* __restrict__ pfx,
    int* __restrict__ rem, int shift)
{
    int b = blockIdx.x;
    int t = threadIdx.x;
    __shared__ unsigned int h[256];
    h[t] = ghist[b * 256 + t];
    ghist[b * 256 + t] = 0u;
    __syncthreads();
    if (t == 0) {
        int r = rem[b];
        unsigned int bsel = 0u;
        for (int bin = 255; bin >= 0; bin--) {
            int c = (int)h[bin];
            if (c >= r) { bsel = (unsigned int)bin; break; }
            r -= c;
        }
        rem[b] = r;
        pfx[b] |= bsel << shift;
    }
}

// ---------------- top-k: write mask for >T, count ties per chunk --------------
__global__ __launch_bounds__(256) void topk_mask1(
    const float* __restrict__ imp, const unsigned int* __restrict__ pfx,
    float* __restrict__ mask, int* __restrict__ blocktie)
{
    int b = blockIdx.x / NCHUNK, ch = blockIdx.x % NCHUNK;
    int t = threadIdx.x;
    unsigned int T = pfx[b];
    float4 v = ((const float4*)(imp + b * PPIX + ch * 1024))[t];
    unsigned int bb[4] = {__float_as_uint(v.x), __float_as_uint(v.y),
                          __float_as_uint(v.z), __float_as_uint(v.w)};
    float4 mo;
    float* mp = &mo.x;
    int cnt = 0;
    #pragma unroll
    for (int k = 0; k < 4; k++) {
        mp[k] = (bb[k] > T) ? 1.f : 0.f;
        cnt += (bb[k] == T) ? 1 : 0;
    }
    ((float4*)(mask + b * PPIX + ch * 1024))[t] = mo;
    #pragma unroll
    for (int off = 32; off > 0; off >>= 1) cnt += __shfl_down(cnt, off);
    __shared__ int ws4[4];
    int lane = t & 63, wv = t >> 6;
    if (lane == 0) ws4[wv] = cnt;
    __syncthreads();
    if (t == 0) blocktie[b * NCHUNK + ch] = ws4[0] + ws4[1] + ws4[2] + ws4[3];
}

// ---------------- top-k: set first `rem` ties in index order ------------------
__global__ __launch_bounds__(256) void topk_mask2(
    const float* __restrict__ imp, const unsigned int* __restrict__ pfx,
    const int* __restrict__ rem_, const int* __restrict__ blocktie,
    float* __restrict__ mask)
{
    int b = blockIdx.x;
    int t = threadIdx.x, lane = t & 63, wv = t >> 6;
    unsigned int T = pfx[b];
    int rem = rem_[b];
    __shared__ int sbase[NCHUNK], scnt[NCHUNK];
    if (t == 0) {
        int s = 0;
        for (int i = 0; i < NCHUNK; i++) {
            sbase[i] = s;
            int c = blocktie[b * NCHUNK + i];
            scnt[i] = c;
            s += c;
        }
    }
    __syncthreads();
    __shared__ int wtot[4];
    for (int ch = 0; ch < NCHUNK; ch++) {
        if (scnt[ch] == 0) continue;
        int base = sbase[ch];
        if (base >= rem) break;
        for (int g = 0; g < 4; g++) {
            int i = b * PPIX + ch * 1024 + g * 256 + t;
            int flag = (__float_as_uint(imp[i]) == T) ? 1 : 0;
            unsigned long long bal = __ballot(flag);
            if (lane == 0) wtot[wv] = __popcll(bal);
            __syncthreads();
            int wbase = 0, tot = 0;
            for (int q = 0; q < 4; q++) { int c = wtot[q]; if (q < wv) wbase += c; tot += c; }
            if (flag && base + wbase + __popcll(bal & ((1ull << lane) - 1ull)) < rem)
                mask[i] = 1.f;
            base += tot;
            __syncthreads();
        }
    }
}

// ---------------- level 0: masked dwconv3x3 -> MFMA 1x1, y0(bf16) + partials --
__global__ __launch_bounds__(256, 4) void level0_kernel(
    const float* __restrict__ x, const float* __restrict__ mask,
    const float* __restrict__ w_in, const float* __restrict__ b_in,
    const float* __restrict__ dw_w, const float* __restrict__ pw_w,
    const float* __restrict__ pw_b,
    unsigned short* __restrict__ y_out, float* __restrict__ partials)
{
    __shared__ __align__(16) short sW[4096];
    __shared__ __align__(16) short sP[4096];
    __shared__ float sred[128];
    __shared__ float sBias[64];
    char* sWc = (char*)sW; char* sPc = (char*)sP;
    int t = threadIdx.x;
    int swz = (blockIdx.x & 7) * 784 + (blockIdx.x >> 3);
    int b = swz / 784;
    int l = t & 63, og = t >> 6;
    int p0 = (swz % 784) * 64;
    int p = p0 + l;
    int h = p / WDIM, w = p % WDIM;
    stage_w64(pw_w, sWc, t);
    if (t < 64) sBias[t] = pw_b[t];

    int rowoff[3]; float okhf[3];
    int wcs[3]; float okwf[3];
    #pragma unroll
    for (int k = 0; k < 3; k++) {
        int hh = h + k - 1;
        okhf[k] = (hh >= 0 && hh < HDIM) ? 1.f : 0.f;
        rowoff[k] = min(max(hh, 0), HDIM - 1) * WDIM;
        int ww = w + k - 1;
        okwf[k] = (ww >= 0 && ww < WDIM) ? 1.f : 0.f;
        wcs[k] = min(max(ww, 0), WDIM - 1);
    }
    float mv[9], mxv[9];
    const float* mb = mask + b * PPIX;
    const float* xb = x + b * PPIX;
    #pragma unroll
    for (int ky = 0; ky < 3; ky++) {
        #pragma unroll
        for (int kx = 0; kx < 3; kx++) {
            int a = rowoff[ky] + wcs[kx];
            float mm = mb[a] * (okhf[ky] * okwf[kx]);
            mv[ky * 3 + kx] = mm;
            mxv[ky * 3 + kx] = mm * xb[a];
        }
    }
    bf8_t pk0, pk1;
    #pragma unroll
    for (int j = 0; j < 16; j++) {
        int c = og * 16 + j;
        float wk = w_in[64 + c], bk = b_in[64 + c];
        const float* dwr = dw_w + c * 9;
        float a0 = 0.f, a1 = 0.f;
        #pragma unroll
        for (int tp = 0; tp < 9; tp++) {
            float dv = dwr[tp];
            a0 += dv * mxv[tp];
            a1 += dv * mv[tp];
        }
        unsigned short bv = f2bf(wk * a0 + bk * a1);
        if (j < 8) pk0[j] = (short)bv; else pk1[j - 8] = (short)bv;
    }
    int gl = ldsg(l);
    *(bf8_t*)(sPc + l * 128 + (((2 * og) ^ gl) << 4)) = pk0;
    *(bf8_t*)(sPc + l * 128 + (((2 * og + 1) ^ gl) << 4)) = pk1;
    __syncthreads();

    int m0 = og * 16, lr = l & 15, lg = l >> 4;
    f4_t acc[4];
    mfma64(sWc, sPc, l, m0, acc);
    unsigned short* ybase = y_out + (size_t)b * 64 * PPIX + p0;
    #pragma unroll
    for (int r = 0; r < 4; r++) {
        int o = m0 + 4 * lg + r;
        float bias = sBias[o];
        float s = 0.f, s2 = 0.f;
        #pragma unroll
        for (int nt = 0; nt < 4; nt++) {
            float yv = acc[nt][r] + bias;
            ybase[(size_t)o * PPIX + nt * 16 + lr] = f2bf(yv);
            s += yv; s2 += yv * yv;
        }
        #pragma unroll
        for (int m = 1; m < 16; m <<= 1) {
            s += __shfl_xor(s, m);
            s2 += __shfl_xor(s2, m);
        }
        if (lr == 0) { sred[2 * o] = s; sred[2 * o + 1] = s2; }
    }
    __syncthreads();
    if (t < 128) partials[(size_t)blockIdx.x * 128 + t] = sred[t];
}

// ---------------- dilated dwconv: bf16 in/out, register-sliding ---------------
// compute mapping ROW-FASTEST (row=t&15, xs=t>>4): b128 reads spread across all
// 8 bank quads (best measured config, r14: 69us).
template<int KSZ, int DIL>
__global__ __launch_bounds__(256, 4) void dw_kernel(
    const unsigned short* __restrict__ in, const float* __restrict__ bnp,
    const float* __restrict__ dw_w, unsigned short* __restrict__ out)
{
    constexpr int PAD = (KSZ / 2) * DIL;
    constexpr int BH = 16;
    constexpr int LR = BH + 2 * PAD;
    constexpr int SW = WDIM + 2 * PAD + 4;    // %4==0; %32 = 28 (7,4) / 12 (5,2)
    constexpr int SEG = 16 + 2 * PAD;
    __shared__ float sIn[LR * SW];

    int t = threadIdx.x;
    int swz = (blockIdx.x & 7) * (NDWBLK / 8) + (blockIdx.x >> 3);
    int bc = swz / NBAND, band = swz % NBAND;
    int c = bc & 63;
    int r0 = band * BH;
    float sc = bnp[c], sh = bnp[64 + c];
    const unsigned short* plane = in + (size_t)bc * PPIX;

    constexpr int PADC = SW - WDIM;
    for (int i = t; i < LR * PADC; i += 256) {
        int r = i / PADC, cc = i % PADC;
        int col = (cc < PAD) ? cc : (cc + WDIM);
        sIn[r * SW + col] = 0.f;
    }
    for (int i = t; i < LR * 28; i += 256) {
        int sr = i / 28, q = i % 28;
        int gr = r0 - PAD + sr;
        float4 a = {0.f, 0.f, 0.f, 0.f}, bq = {0.f, 0.f, 0.f, 0.f};
        if (gr >= 0 && gr < HDIM) {
            us8_t v = *(const us8_t*)(plane + gr * WDIM + 8 * q);
            a.x = fmaxf(sc * bf2f(v[0]) + sh, 0.f);
            a.y = fmaxf(sc * bf2f(v[1]) + sh, 0.f);
            a.z = fmaxf(sc * bf2f(v[2]) + sh, 0.f);
            a.w = fmaxf(sc * bf2f(v[3]) + sh, 0.f);
            bq.x = fmaxf(sc * bf2f(v[4]) + sh, 0.f);
            bq.y = fmaxf(sc * bf2f(v[5]) + sh, 0.f);
            bq.z = fmaxf(sc * bf2f(v[6]) + sh, 0.f);
            bq.w = fmaxf(sc * bf2f(v[7]) + sh, 0.f);
        }
        *(float4*)(sIn + sr * SW + PAD + 8 * q) = a;
        *(float4*)(sIn + sr * SW + PAD + 8 * q + 4) = bq;
    }
    __syncthreads();

    if (t < 224) {   // no barriers below; idle tail predicated
        const float* dwr = dw_w + c * KSZ * KSZ;
        float wk[KSZ * KSZ];
        #pragma unroll
        for (int i = 0; i < KSZ * KSZ; i++) wk[i] = dwr[i];

        int row = t & 15, xs = t >> 4;     // row-fastest: 16 rows x 14 strips
        int x0 = xs * 16;
        float acc[16];
        #pragma unroll
        for (int j = 0; j < 16; j++) acc[j] = 0.f;
        #pragma unroll
        for (int ky = 0; ky < KSZ; ky++) {
            const float4* srow = (const float4*)(sIn + (row + ky * DIL) * SW + x0);
            float s[SEG];
            #pragma unroll
            for (int i = 0; i < SEG / 4; i++) ((float4*)s)[i] = srow[i];
            #pragma unroll
            for (int kx = 0; kx < KSZ; kx++) {
                float wv = wk[ky * KSZ + kx];
                #pragma unroll
                for (int j = 0; j < 16; j++)
                    acc[j] += s[j + DIL * kx] * wv;
            }
        }
        us8_t o0, o1;
        #pragma unroll
        for (int j = 0; j < 8; j++) { o0[j] = f2bf(acc[j]); o1[j] = f2bf(acc[8 + j]); }
        unsigned short* orow = out + (size_t)bc * PPIX + (r0 + row) * WDIM + x0;
        *(us8_t*)orow = o0;
        *(us8_t*)(orow + 8) = o1;
    }
}

// ---------------- pointwise 64x64 MFMA matvec, OUT-OF-PLACE, + bn partials ----
__global__ __launch_bounds__(256, 4) void pw_kernel(
    const float* __restrict__ pw_w, const float* __restrict__ pw_b,
    const unsigned short* __restrict__ src_y, unsigned short* __restrict__ dst_y,
    float* __restrict__ partials)
{
    __shared__ __align__(16) short sW[4096];
    __shared__ __align__(16) short sP[4096];
    __shared__ float sred[128];
    __shared__ float sBias[64];
    char* sWc = (char*)sW; char* sPc = (char*)sP;
    int t = threadIdx.x;
    int swz = (blockIdx.x & 7) * 784 + (blockIdx.x >> 3);
    int b = swz / 784;
    int p0 = (swz % 784) * 64;
    stage_w64(pw_w, sWc, t);
    if (t < 64) sBias[t] = pw_b[t];

    const unsigned short* sbase_g = src_y + (size_t)b * 64 * PPIX + p0;
    unsigned short* dbase_g = dst_y + (size_t)b * 64 * PPIX + p0;
    {
        int c = t >> 2, pg = t & 3;
        const unsigned short* src = sbase_g + (size_t)c * PPIX + 16 * pg;
        us8_t v0 = *(const us8_t*)src;
        us8_t v1 = *(const us8_t*)(src + 8);
        int kc = c >> 3, cb = 2 * (c & 7);
        #pragma unroll
        for (int e = 0; e < 16; e++) {
            int r = 16 * pg + e;
            int gr = ldsg(r);
            unsigned short val = (e < 8) ? (unsigned short)v0[e] : (unsigned short)v1[e - 8];
            *(unsigned short*)(sPc + r * 128 + ((kc ^ gr) << 4) + cb) = val;
        }
    }
    __syncthreads();

    int l = t & 63, wv = t >> 6, m0 = wv * 16;
    int lr = l & 15, lg = l >> 4;
    f4_t acc[4];
    mfma64(sWc, sPc, l, m0, acc);
    #pragma unroll
    for (int r = 0; r < 4; r++) {
        int o = m0 + 4 * lg + r;
        float bias = sBias[o];
        float s = 0.f, s2 = 0.f;
        #pragma unroll
        for (int nt = 0; nt < 4; nt++) {
            float yv = acc[nt][r] + bias;
            dbase_g[(size_t)o * PPIX + nt * 16 + lr] = f2bf(yv);
            s += yv; s2 += yv * yv;
        }
        #pragma unroll
        for (int m = 1; m < 16; m <<= 1) {
            s += __shfl_xor(s, m);
            s2 += __shfl_xor(s2, m);
        }
        if (lr == 0) { sred[2 * o] = s; sred[2 * o + 1] = s2; }
    }
    __syncthreads();
    if (t < 128) partials[(size_t)blockIdx.x * 128 + t] = sred[t];
}

// ---------------- bn finalize: tree-reduce partials, one block per channel ----
__global__ __launch_bounds__(256) void bnfin_kernel(
    const float* __restrict__ partials,
    const float* __restrict__ g, const float* __restrict__ be,
    float* __restrict__ bnp)
{
    int c = blockIdx.x;
    int t = threadIdx.x;
    float s = 0.f, s2 = 0.f;
    for (int blk = t; blk < NBLK; blk += 256) {
        s  += partials[(size_t)blk * 128 + 2 * c];
        s2 += partials[(size_t)blk * 128 + 2 * c + 1];
    }
    #pragma unroll
    for (int off = 32; off > 0; off >>= 1) {
        s += __shfl_down(s, off);
        s2 += __shfl_down(s2, off);
    }
    __shared__ float wsm[8];
    int lane = t & 63, wv = t >> 6;
    if (lane == 0) { wsm[wv] = s; wsm[4 + wv] = s2; }
    __syncthreads();
    if (t == 0) {
        s = wsm[0] + wsm[1] + wsm[2] + wsm[3];
        s2 = wsm[4] + wsm[5] + wsm[6] + wsm[7];
        const float inv_n = 1.f / (float)NPIX;
        float mu = s * inv_n;
        float var = s2 * inv_n - mu * mu;
        float sc = g[c] * rsqrtf(var + 1e-5f);
        bnp[c] = sc;
        bnp[64 + c] = be[c] - mu * sc;
    }
}

// ---------------- K_global: per (b,c) spatial mean of relu(bn(y2)) ------------
__global__ __launch_bounds__(1024) void kglobal_kernel(
    const unsigned short* __restrict__ y2, const float* __restrict__ bnp2,
    float* __restrict__ kg)
{
    int bc = blockIdx.x;
    int c = bc & 63;
    int t = threadIdx.x;
    const unsigned short* row = y2 + (size_t)bc * PPIX;
    float sc = bnp2[c], sh = bnp2[64 + c];
    float s = 0.f;
    for (int ii = t; ii < PPIX / 8; ii += 1024) {
        us8_t v = *(const us8_t*)(row + 8 * ii);
        #pragma unroll
        for (int k = 0; k < 8; k++) s += fmaxf(sc * bf2f(v[k]) + sh, 0.f);
    }
    #pragma unroll
    for (int off = 32; off > 0; off >>= 1) s += __shfl_down(s, off);
    __shared__ float wsum[16];
    int lane = t & 63, wv = t >> 6;
    if (lane == 0) wsum[wv] = s;
    __syncthreads();
    if (t == 0) {
        float tot = 0.f;
        #pragma unroll
        for (int q = 0; q < 16; q++) tot += wsum[q];
        kg[bc] = tot * (1.f / (float)PPIX);
    }
}

// ---------------- final: aggregate + MFMA V + QV + MFMA O + x_proj ------------
__global__ __launch_bounds__(256, 4) void final_kernel(
    const float* __restrict__ x, const float* __restrict__ w_in,
    const float* __restrict__ b_in,
    const unsigned short* __restrict__ y0, const unsigned short* __restrict__ y1,
    const unsigned short* __restrict__ y2,
    const float* __restrict__ bnp, const float* __restrict__ kg,
    const float* __restrict__ val_w, const float* __restrict__ val_b,
    const float* __restrict__ out_w, const float* __restrict__ out_b,
    const float* __restrict__ coeffs, float* __restrict__ out)
{
    __shared__ __align__(16) short sVW[4096];
    __shared__ __align__(16) short sOW[4096];
    __shared__ __align__(16) short sP[4096];
    __shared__ float sxv[64], sG[320];   // sG stride-5: 2-way max bank alias
    __shared__ float sQW[64], sQB[64], sVB[64], sOB[64], sC1[64], sC2[64];
    char* sVWc = (char*)sVW; char* sOWc = (char*)sOW; char* sPc = (char*)sP;
    int t = threadIdx.x;
    int blk = blockIdx.x;
    int b = blk / 784;
    int l = t & 63, wv = t >> 6;
    int p0 = (blk % 784) * 64;
    stage_w64(val_w, sVWc, t);
    stage_w64(out_w, sOWc, t);
    if (t < 64) {
        sQW[t] = w_in[t]; sQB[t] = b_in[t];
        sVB[t] = val_b[t]; sOB[t] = out_b[t];
        sC1[t] = coeffs[32 + t]; sC2[t] = coeffs[96 + t];
        float xv = x[b * PPIX + p0 + t];
        sxv[t] = xv;
        float g0 = xv * w_in[128] + b_in[128];
        float g1 = xv * w_in[129] + b_in[129];
        float g2 = xv * w_in[130] + b_in[130];
        float g3 = xv * w_in[131] + b_in[131];
        float mx = fmaxf(fmaxf(g0, g1), fmaxf(g2, g3));
        float e0 = expf(g0 - mx), e1 = expf(g1 - mx);
        float e2 = expf(g2 - mx), e3 = expf(g3 - mx);
        float inv = 1.f / (e0 + e1 + e2 + e3);
        sG[5 * t + 0] = e0 * inv;
        sG[5 * t + 1] = e1 * inv;
        sG[5 * t + 2] = e2 * inv;
        sG[5 * t + 3] = e3 * inv;
    }
    __syncthreads();

    // P staging: thread = (channel c, 16-pixel group pg), us8 vector loads
    {
        int c = t >> 2, pg = t & 3;
        size_t base = (size_t)(b * 64 + c) * PPIX + p0 + 16 * pg;
        us8_t a0 = *(const us8_t*)(y0 + base);
        us8_t a1 = *(const us8_t*)(y0 + base + 8);
        us8_t q0 = *(const us8_t*)(y1 + base);
        us8_t q1 = *(const us8_t*)(y1 + base + 8);
        us8_t r0 = *(const us8_t*)(y2 + base);
        us8_t r1 = *(const us8_t*)(y2 + base + 8);
        float s0 = bnp[c],       h0 = bnp[64 + c];
        float s1 = bnp[128 + c], h1 = bnp[192 + c];
        float s2 = bnp[256 + c], h2 = bnp[320 + c];
        float kgc = kg[b * 64 + c];
        int kc = c >> 3, cb = 2 * (c & 7);
        #pragma unroll
        for (int e = 0; e < 16; e++) {
            unsigned short u0 = (e < 8) ? (unsigned short)a0[e] : (unsigned short)a1[e - 8];
            unsigned short u1 = (e < 8) ? (unsigned short)q0[e] : (unsigned short)q1[e - 8];
            unsigned short u2 = (e < 8) ? (unsigned short)r0[e] : (unsigned short)r1[e - 8];
            float f0 = fmaxf(s0 * bf2f(u0) + h0, 0.f);
            float f1 = fmaxf(s1 * bf2f(u1) + h1, 0.f);
            float f2 = fmaxf(s2 * bf2f(u2) + h2, 0.f);
            int r = 16 * pg + e;
            float kf = sG[5 * r] * f0 + sG[5 * r + 1] * f1
                     + sG[5 * r + 2] * f2 + sG[5 * r + 3] * kgc;
            int gr = ldsg(r);
            *(unsigned short*)(sPc + r * 128 + ((kc ^ gr) << 4) + cb) = f2bf(kf);
        }
    }
    __syncthreads();

    int m0 = wv * 16, lr = l & 15, lg = l >> 4;
    f4_t accV[4];
    mfma64(sVWc, sPc, l, m0, accV);
    __syncthreads();   // all P reads done before QV overwrite

    #pragma unroll
    for (int nt = 0; nt < 4; nt++) {
        float xvp = sxv[nt * 16 + lr];
        us4_t q4;
        #pragma unroll
        for (int r = 0; r < 4; r++) {
            int o = m0 + 4 * lg + r;
            float V = accV[nt][r] + sVB[o];
            float q = xvp * sQW[o] + sQB[o];
            q4[r] = f2bf(q * V);
        }
        int rb = nt * 16 + lr, gb = ldsg(rb);
        int kc = 2 * wv + (lg >> 1);
        *(us4_t*)(sPc + rb * 128 + ((kc ^ gb) << 4) + 8 * (lg & 1)) = q4;
    }
    __syncthreads();

    f4_t accO[4];
    mfma64(sOWc, sPc, l, m0, accO);
    #pragma unroll
    for (int nt = 0; nt < 4; nt++) {
        float xvp = sxv[nt * 16 + lr];
        #pragma unroll
        for (int r = 0; r < 4; r++) {
            int o = m0 + 4 * lg + r;
            out[(size_t)(b * 64 + o) * PPIX + p0 + nt * 16 + lr] =
                accO[nt][r] + sOB[o] + xvp * sC1[o] + sC2[o];
        }
    }
}

extern "C" void kernel_launch(void* const* d_in, const int* in_sizes, int n_in,
                              void* d_out, int out_size, void* d_ws, size_t ws_size,
                              hipStream_t stream)
{
    (void)in_sizes; (void)n_in; (void)out_size; (void)ws_size;
    const float* x      = (const float*)d_in[0];
    const float* w_in   = (const float*)d_in[1];
    const float* b_in   = (const float*)d_in[2];
    const float* dw0    = (const float*)d_in[3];
    const float* pw0_w  = (const float*)d_in[4];
    const float* pw0_b  = (const float*)d_in[5];
    const float* bn0_g  = (const float*)d_in[6];
    const float* bn0_b  = (const float*)d_in[7];
    const float* dw1    = (const float*)d_in[8];
    const float* pw1_w  = (const float*)d_in[9];
    const float* pw1_b  = (const float*)d_in[10];
    const float* bn1_g  = (const float*)d_in[11];
    const float* bn1_b  = (const float*)d_in[12];
    const float* dw2    = (const float*)d_in[13];
    const float* pw2_w  = (const float*)d_in[14];
    const float* pw2_b  = (const float*)d_in[15];
    const float* bn2_g  = (const float*)d_in[16];
    const float* bn2_b  = (const float*)d_in[17];
    const float* imp_w1 = (const float*)d_in[18];
    const float* imp_b1 = (const float*)d_in[19];
    const float* imp_w2 = (const float*)d_in[20];
    const float* imp_b2 = (const float*)d_in[21];
    const float* val_w  = (const float*)d_in[22];
    const float* val_b  = (const float*)d_in[23];
    const float* out_w  = (const float*)d_in[24];
    const float* out_b  = (const float*)d_in[25];
    const float* fin_w  = (const float*)d_in[26];
    const float* fin_b  = (const float*)d_in[27];

    unsigned short* y0 = (unsigned short*)d_ws;
    unsigned short* y1 = y0 + (size_t)NELEM;
    unsigned short* y2 = y1 + (size_t)NELEM;
    unsigned short* yt = y2 + (size_t)NELEM;           // dwconv temp
    float* imp  = (float*)(yt + (size_t)NELEM);
    float* mask = imp + NPIX;
    float* partials = mask + NPIX;                // 6272*128
    float* bnp   = partials + (size_t)NBLK * 128; // 3*128
    float* kg    = bnp + 384;                     // 512
    float* coeffs = kg + 512;                     // 160
    unsigned int* ghist = (unsigned int*)(coeffs + 160);   // 8*256
    unsigned int* pfx   = ghist + 2048;                    // 8
    int* rem            = (int*)(pfx + 8);                 // 8
    int* blocktie       = rem + 8;                         // 8*49
    float* outp = (float*)d_out;

    prep_kernel<<<1, 256, 0, stream>>>(w_in, b_in, imp_w1, imp_b1, fin_w, fin_b,
                                       coeffs, ghist, pfx, rem);
    imp_kernel<<<NPIX / 256, 256, 0, stream>>>(x, coeffs, imp_w2, imp_b2, imp);

    for (int shift = 24; shift >= 0; shift -= 8) {
        topk_hist<<<BATCH * NCHUNK, 256, 0, stream>>>(imp, pfx, ghist, shift);
        topk_select<<<BATCH, 256, 0, stream>>>(ghist, pfx, rem, shift);
    }
    topk_mask1<<<BATCH * NCHUNK, 256, 0, stream>>>(imp, pfx, mask, blocktie);
    topk_mask2<<<BATCH, 256, 0, stream>>>(imp, pfx, rem, blocktie, mask);

    level0_kernel<<<NBLK, 256, 0, stream>>>(x, mask, w_in, b_in, dw0, pw0_w, pw0_b,
                                            y0, partials);
    bnfin_kernel<<<64, 256, 0, stream>>>(partials, bn0_g, bn0_b, bnp);

    dw_kernel<5, 2><<<NDWBLK, 256, 0, stream>>>(y0, bnp, dw1, yt);
    pw_kernel<<<NBLK, 256, 0, stream>>>(pw1_w, pw1_b, yt, y1, partials);
    bnfin_kernel<<<64, 256, 0, stream>>>(partials, bn1_g, bn1_b, bnp + 128);

    dw_kernel<7, 4><<<NDWBLK, 256, 0, stream>>>(y1, bnp + 128, dw2, yt);
    pw_kernel<<<NBLK, 256, 0, stream>>>(pw2_w, pw2_b, yt, y2, partials);
    bnfin_kernel<<<64, 256, 0, stream>>>(partials, bn2_g, bn2_b, bnp + 256);

    kglobal_kernel<<<512, 1024, 0, stream>>>(y2, bnp + 256, kg);
    final_kernel<<<NBLK, 256, 0, stream>>>(x, w_in, b_in, y0, y1, y2, bnp, kg,
                                           val_w, val_b, out_w, out_b, coeffs, outp);
}